// Round 1
// baseline (12696.236 us; speedup 1.0000x reference)
//
#include <hip/hip_runtime.h>
#include <hip/hip_bf16.h>
#include <math.h>

// ---------------------------------------------------------------------------
// BashTransformer forward on MI355X. Round 1: correct-first, all fp32.
// h=embed[ids]; delta-read; 6x(attn+FFN); delta-write; final norm; logits.
// ---------------------------------------------------------------------------

#define LSEQ 1024
#define BATCH 4
#define HIDDEN 512
#define NHEAD 8
#define HDIM 64
#define SHEAD 8
#define SDHD 32
#define SDIMM 256
#define FFND 1536
#define VOCN 63

// ------------------------------- rope tables -------------------------------
__global__ void rope_tables_k(float* __restrict__ cosT, float* __restrict__ sinT) {
    int idx = blockIdx.x * 256 + threadIdx.x;   // 32768 = 1024*32
    int l = idx >> 5, d = idx & 31;
    double ang = (double)l * pow(500000.0, -(double)(2 * d) / 64.0);
    cosT[idx] = (float)cos(ang);
    sinT[idx] = (float)sin(ang);
}

// ------------------------------- embedding ---------------------------------
__global__ void embed_k(const int* __restrict__ ids, const float* __restrict__ emb,
                        float* __restrict__ h) {
    int tok = blockIdx.x;
    int id = ids[tok];
    ((float4*)(h + (size_t)tok * HIDDEN))[threadIdx.x] =
        ((const float4*)(emb + (size_t)id * HIDDEN))[threadIdx.x];
}

// ------------------------------- rmsnorm (512) -----------------------------
__global__ void rmsnorm512(const float* __restrict__ in, const float* __restrict__ w,
                           float* __restrict__ out) {
    int row = blockIdx.x, t = threadIdx.x;     // 128 threads
    float4 x = ((const float4*)(in + (size_t)row * 512))[t];
    float s = x.x * x.x + x.y * x.y + x.z * x.z + x.w * x.w;
    for (int m = 1; m < 64; m <<= 1) s += __shfl_xor(s, m);
    __shared__ float red[2];
    if ((t & 63) == 0) red[t >> 6] = s;
    __syncthreads();
    float tot = red[0] + red[1];
    float r = rsqrtf(tot * (1.f / 512.f) + 1e-6f);
    float4 wv = ((const float4*)w)[t];
    float4 o;
    o.x = x.x * r * wv.x; o.y = x.y * r * wv.y;
    o.z = x.z * r * wv.z; o.w = x.w * r * wv.w;
    ((float4*)(out + (size_t)row * 512))[t] = o;
}

// ------------------------------- GEMM C = A @ B^T --------------------------
// A: MxK row-major, B: NxK row-major, C: MxN.
// MODE 0: store   MODE 1: C += acc   MODE 2: C = sigmoid(acc + bias[c])
// MODE 4: C = silu(C_old) * acc   (for FFN gate*up fusion)
template <int MODE>
__global__ __launch_bounds__(256) void gemm_nt(const float* __restrict__ A,
                                               const float* __restrict__ B,
                                               float* __restrict__ C,
                                               const float* __restrict__ bias,
                                               int M, int N, int K) {
    __shared__ __align__(16) float As[16][132];  // [kk][r], 128 rows
    __shared__ __align__(16) float Bs[16][68];   // [kk][c], 64 cols
    int tx = threadIdx.x & 15, ty = threadIdx.x >> 4;
    int row0 = blockIdx.y * 128, col0 = blockIdx.x * 64;
    float acc[8][4] = {};
    for (int k0 = 0; k0 < K; k0 += 16) {
        for (int e = threadIdx.x; e < 2048; e += 256) {
            int r = e >> 4, kk = e & 15;
            As[kk][r] = A[(size_t)(row0 + r) * K + k0 + kk];
        }
        for (int e = threadIdx.x; e < 1024; e += 256) {
            int cn = e >> 4, kk = e & 15;
            int col = col0 + cn;
            Bs[kk][cn] = (col < N) ? B[(size_t)col * K + k0 + kk] : 0.f;
        }
        __syncthreads();
#pragma unroll
        for (int kk = 0; kk < 16; ++kk) {
            float4 a0 = *(const float4*)&As[kk][ty * 8];
            float4 a1 = *(const float4*)&As[kk][ty * 8 + 4];
            float4 bv = *(const float4*)&Bs[kk][tx * 4];
            float av[8] = {a0.x, a0.y, a0.z, a0.w, a1.x, a1.y, a1.z, a1.w};
            float bb[4] = {bv.x, bv.y, bv.z, bv.w};
#pragma unroll
            for (int i = 0; i < 8; ++i)
#pragma unroll
                for (int j = 0; j < 4; ++j) acc[i][j] += av[i] * bb[j];
        }
        __syncthreads();
    }
#pragma unroll
    for (int i = 0; i < 8; ++i) {
        int r = row0 + ty * 8 + i;
#pragma unroll
        for (int j = 0; j < 4; ++j) {
            int c = col0 + tx * 4 + j;
            if (c < N) {
                size_t o = (size_t)r * N + c;
                float v = acc[i][j];
                if (MODE == 0) C[o] = v;
                else if (MODE == 1) C[o] += v;
                else if (MODE == 2) C[o] = 1.f / (1.f + expf(-(v + bias[c])));
                else if (MODE == 4) {
                    float g = C[o];
                    C[o] = g / (1.f + expf(-g)) * v;
                }
            }
        }
    }
}

// ------------------------------- RoPE --------------------------------------
__global__ void rope_apply(float* __restrict__ Q, float* __restrict__ Kb,
                           const float* __restrict__ cosT, const float* __restrict__ sinT) {
    int tok = blockIdx.x;
    int l = tok & (LSEQ - 1);
    int hh = threadIdx.x >> 5, d = threadIdx.x & 31;   // 8 heads x 32 pairs
    float c = cosT[l * 32 + d], s = sinT[l * 32 + d];
    float* q = Q + (size_t)tok * HIDDEN + hh * HDIM;
    float* k = Kb + (size_t)tok * HIDDEN + hh * HDIM;
    float q1 = q[d], q2 = q[d + 32];
    q[d] = q1 * c - q2 * s;
    q[d + 32] = q2 * c + q1 * s;
    float k1 = k[d], k2 = k[d + 32];
    k[d] = k1 * c - k2 * s;
    k[d + 32] = k2 * c + k1 * s;
}

// ------------------------------- attention ---------------------------------
// grid (128 qtiles of 8 rows, 8 heads, 4 batch), 256 threads.
__global__ __launch_bounds__(256) void attn_k(const float* __restrict__ Q,
                                              const float* __restrict__ K,
                                              const float* __restrict__ V,
                                              float* __restrict__ O) {
    int t = blockIdx.x, hh = blockIdx.y, b = blockIdx.z;
    int l0 = t * 8;
    __shared__ __align__(16) float sc[8][1025];
    __shared__ __align__(16) float qt[8][64];
    __shared__ float red[8][32];
    __shared__ float rowm[8], rows[8];

    if (threadIdx.x < 128) {
        int e = threadIdx.x;
        int r = e >> 4, d4 = e & 15;
        *(float4*)&qt[r][d4 * 4] =
            *(const float4*)(Q + ((size_t)(b * LSEQ + l0 + r) * HIDDEN) + hh * HDIM + d4 * 4);
    }
    __syncthreads();
    int r = threadIdx.x & 7, c = threadIdx.x >> 3;  // c in 0..31
    int jmax = l0 + r;
    // scores
    for (int j = c; j < l0 + 8; j += 32) {
        if (j <= jmax) {
            const float4* kp = (const float4*)(K + ((size_t)(b * LSEQ + j) * HIDDEN) + hh * HDIM);
            float s = 0.f;
#pragma unroll
            for (int d4 = 0; d4 < 16; ++d4) {
                float4 kv = kp[d4];
                float4 qv = *(const float4*)&qt[r][d4 * 4];
                s += qv.x * kv.x + qv.y * kv.y + qv.z * kv.z + qv.w * kv.w;
            }
            sc[r][j] = s * 0.125f;
        }
    }
    __syncthreads();
    // row max
    float m = -1e30f;
    for (int j = c; j <= jmax; j += 32) m = fmaxf(m, sc[r][j]);
    red[r][c] = m;
    __syncthreads();
    if (c == 0) {
        float mm = -1e30f;
        for (int x = 0; x < 32; ++x) mm = fmaxf(mm, red[r][x]);
        rowm[r] = mm;
    }
    __syncthreads();
    float mrow = rowm[r];
    float sum = 0.f;
    for (int j = c; j <= jmax; j += 32) {
        float e = __expf(sc[r][j] - mrow);
        sc[r][j] = e;
        sum += e;
    }
    red[r][c] = sum;
    __syncthreads();
    if (c == 0) {
        float ss = 0.f;
        for (int x = 0; x < 32; ++x) ss += red[r][x];
        rows[r] = ss;
    }
    __syncthreads();
    // PV: thread covers (r, d=2c .. 2c+1)
    float inv = 1.f / rows[r];
    float ax = 0.f, ay = 0.f;
    const float* vbase = V + ((size_t)(b * LSEQ) * HIDDEN) + hh * HDIM + c * 2;
    for (int j = 0; j <= jmax; ++j) {
        float p = sc[r][j];
        float2 vv = *(const float2*)(vbase + (size_t)j * HIDDEN);
        ax += p * vv.x;
        ay += p * vv.y;
    }
    float2 o;
    o.x = ax * inv;
    o.y = ay * inv;
    *(float2*)(O + ((size_t)(b * LSEQ + l0 + r) * HIDDEN) + hh * HDIM + c * 2) = o;
}

// ------------------------------- delta scan --------------------------------
// grid 32 = (b, head); 1024 threads, thread (i=t>>5, j=t&31) owns S[i][j].
__global__ __launch_bounds__(1024) void delta_scan(
    const float* __restrict__ kp, const float* __restrict__ vp,
    const float* __restrict__ qp, const float* __restrict__ bp,
    const float* __restrict__ ap, const float* __restrict__ S_in,
    float* __restrict__ S_out, float* __restrict__ ctx) {
    int blk = blockIdx.x;
    int b = blk >> 3, hh = blk & 7;
    int i = threadIdx.x >> 5, j = threadIdx.x & 31;
    float S = S_in[((size_t)(b * SHEAD + hh) * SDHD + i) * SDHD + j];
    __shared__ float ks[64][33], vs[64][33], qs[64][33], bs[64][33], as_[64][33];
    __shared__ float rn[64];
    for (int c0 = 0; c0 < LSEQ; c0 += 64) {
        __syncthreads();
        for (int e = threadIdx.x; e < 2048; e += 1024) {
            int l = e >> 5, jj = e & 31;
            size_t g = ((size_t)(b * LSEQ + c0 + l) * SDIMM) + hh * SDHD + jj;
            ks[l][jj] = kp[g];
            vs[l][jj] = vp[g];
            qs[l][jj] = qp[g];
            bs[l][jj] = bp[g];
            as_[l][jj] = ap[g];
        }
        __syncthreads();
        if (threadIdx.x < 64) {
            int l = threadIdx.x;
            float s = 0.f;
#pragma unroll
            for (int x = 0; x < 32; ++x) {
                float kv = ks[l][x];
                s += kv * kv;
            }
            rn[l] = 1.f / fmaxf(sqrtf(s), 1e-12f);
        }
        __syncthreads();
        for (int lc = 0; lc < 64; ++lc) {
            float kj = ks[lc][j] * rn[lc];
            float ai = as_[lc][i], bi = bs[lc][i], vi = vs[lc][i], qj = qs[lc][j];
            S *= ai;
            float p = S * kj;
            p += __shfl_xor(p, 1);
            p += __shfl_xor(p, 2);
            p += __shfl_xor(p, 4);
            p += __shfl_xor(p, 8);
            p += __shfl_xor(p, 16);
            S += bi * (vi - p) * kj;
            float rd = S * qj;
            rd += __shfl_xor(rd, 1);
            rd += __shfl_xor(rd, 2);
            rd += __shfl_xor(rd, 4);
            rd += __shfl_xor(rd, 8);
            rd += __shfl_xor(rd, 16);
            if (j == 0) ctx[((size_t)(b * LSEQ + c0 + lc) * SDIMM) + hh * SDHD + i] = rd;
        }
    }
    S_out[((size_t)(b * SHEAD + hh) * SDHD + i) * SDHD + j] = S;
}

// --------------------- ctx = rmsnorm(ctx,nw)*silu(gate) --------------------
__global__ void ctx_post(float* __restrict__ ctx, const float* __restrict__ gate,
                         const float* __restrict__ nw) {
    int row = blockIdx.x, t = threadIdx.x;  // 64 threads
    float4 x = ((const float4*)(ctx + (size_t)row * SDIMM))[t];
    float s = x.x * x.x + x.y * x.y + x.z * x.z + x.w * x.w;
    for (int m = 1; m < 64; m <<= 1) s += __shfl_xor(s, m);
    float r = rsqrtf(s * (1.f / 256.f) + 1e-6f);
    float4 n = ((const float4*)nw)[t];
    float4 g = ((const float4*)(gate + (size_t)row * SDIMM))[t];
    float4 o;
    o.x = x.x * r * n.x * (g.x / (1.f + expf(-g.x)));
    o.y = x.y * r * n.y * (g.y / (1.f + expf(-g.y)));
    o.z = x.z * r * n.z * (g.z / (1.f + expf(-g.z)));
    o.w = x.w * r * n.w * (g.w / (1.f + expf(-g.w)));
    ((float4*)(ctx + (size_t)row * SDIMM))[t] = o;
}

// ---------------------------------------------------------------------------
extern "C" void kernel_launch(void* const* d_in, const int* in_sizes, int n_in,
                              void* d_out, int out_size, void* d_ws, size_t ws_size,
                              hipStream_t stream) {
    (void)in_sizes; (void)n_in; (void)out_size; (void)ws_size;
    const int* ids = (const int*)d_in[0];
    const float* state = (const float*)d_in[1];
    const float* embedw = (const float*)d_in[2];
    auto F = [&](int i) { return (const float*)d_in[i]; };

    float* ws = (float*)d_ws;
    float* H = ws;                      // 4096x512
    float* XN = ws + 2097152;           // 4096x512
    float* A1 = ws + 4194304;           // 4096x1536
    float* A2 = ws + 10485760;          // 4096x512
    float* cosT = ws + 12582912;        // 1024x32
    float* sinT = cosT + 32768;
    float* Sbuf = sinT + 32768;         // 4x8x32x32
    float* out = (float*)d_out;
    float* logits = out;                // 4096x63
    float* Sout = out + 4096 * VOCN;    // 32768

    auto gemm = [&](int mode, const float* A, const float* B, float* C, const float* bias,
                    int M, int N, int K) {
        dim3 grid((N + 63) / 64, M / 128);
        switch (mode) {
            case 0: gemm_nt<0><<<grid, 256, 0, stream>>>(A, B, C, bias, M, N, K); break;
            case 1: gemm_nt<1><<<grid, 256, 0, stream>>>(A, B, C, bias, M, N, K); break;
            case 2: gemm_nt<2><<<grid, 256, 0, stream>>>(A, B, C, bias, M, N, K); break;
            case 4: gemm_nt<4><<<grid, 256, 0, stream>>>(A, B, C, bias, M, N, K); break;
        }
    };

    rope_tables_k<<<128, 256, 0, stream>>>(cosT, sinT);
    embed_k<<<4096, 128, 0, stream>>>(ids, embedw, H);

    auto delta = [&](const float* Wk, const float* Wv, const float* Wq, const float* Wbw,
                     const float* Wbb, const float* Waw, const float* Wab, const float* Wout,
                     const float* nw, const float* gw, const float* S_in, float* S_out) {
        gemm(0, H, Wk, A1 + 0, nullptr, 4096, 256, 512);
        gemm(0, H, Wv, A1 + 1048576, nullptr, 4096, 256, 512);
        gemm(0, H, Wq, A1 + 2097152, nullptr, 4096, 256, 512);
        gemm(2, H, Wbw, A1 + 3145728, Wbb, 4096, 256, 512);
        gemm(2, H, Waw, A1 + 4194304, Wab, 4096, 256, 512);
        gemm(0, H, gw, A1 + 5242880, nullptr, 4096, 256, 512);
        delta_scan<<<32, 1024, 0, stream>>>(A1, A1 + 1048576, A1 + 2097152, A1 + 3145728,
                                            A1 + 4194304, S_in, S_out, A2);
        ctx_post<<<4096, 64, 0, stream>>>(A2, A1 + 5242880, nw);
        gemm(1, A2, Wout, H, nullptr, 4096, 512, 256);
    };

    // delta-read stage (state from input, S -> Sbuf)
    delta(F(3), F(4), F(5), F(6), F(7), F(8), F(9), F(10), F(11), F(12), state, Sbuf);

    for (int i = 0; i < 6; ++i) {
        rmsnorm512<<<4096, 128, 0, stream>>>(H, F(23) + (size_t)i * 512, XN);
        gemm(0, XN, F(24) + (size_t)i * 262144, A1, nullptr, 4096, 512, 512);
        gemm(0, XN, F(25) + (size_t)i * 262144, A1 + 2097152, nullptr, 4096, 512, 512);
        gemm(0, XN, F(26) + (size_t)i * 262144, A1 + 4194304, nullptr, 4096, 512, 512);
        rope_apply<<<4096, 256, 0, stream>>>(A1, A1 + 2097152, cosT, sinT);
        attn_k<<<dim3(128, 8, 4), 256, 0, stream>>>(A1, A1 + 2097152, A1 + 4194304, A2);
        gemm(1, A2, F(27) + (size_t)i * 262144, H, nullptr, 4096, 512, 512);
        rmsnorm512<<<4096, 128, 0, stream>>>(H, F(28) + (size_t)i * 512, XN);
        gemm(0, XN, F(29) + (size_t)i * 786432, A1, nullptr, 4096, 1536, 512);
        gemm(4, XN, F(30) + (size_t)i * 786432, A1, nullptr, 4096, 1536, 512);
        gemm(1, A1, F(31) + (size_t)i * 786432, H, nullptr, 4096, 512, 1536);
    }

    // delta-write stage (state from Sbuf, S -> output)
    delta(F(13), F(14), F(15), F(16), F(17), F(18), F(19), F(20), F(21), F(22), Sbuf, Sout);

    rmsnorm512<<<4096, 128, 0, stream>>>(H, F(32), XN);
    gemm(0, XN, embedw, logits, nullptr, 4096, VOCN, 512);
}

// Round 2
// 5349.933 us; speedup vs baseline: 2.3732x; 2.3732x over previous
//
#include <hip/hip_runtime.h>
#include <hip/hip_bf16.h>
#include <math.h>

// ---------------------------------------------------------------------------
// BashTransformer forward on MI355X. Round 2: bf16 MFMA GEMMs (m97 structure),
// fused QKV / gate-up / delta projections, fp32 attention + scan.
// ---------------------------------------------------------------------------

#define LSEQ 1024
#define BATCH 4
#define HIDDEN 512
#define NHEAD 8
#define HDIM 64
#define SHEAD 8
#define SDHD 32
#define SDIMM 256
#define FFND 1536
#define VOCN 63

typedef __bf16 bf16;
typedef __attribute__((ext_vector_type(8))) __bf16 bf16x8;
typedef __attribute__((ext_vector_type(4))) float floatx4;

union BF4 { bf16 h[4]; short4 p; };
union BF2 { bf16 h[2]; unsigned u; };

__device__ __forceinline__ void gload16(const void* g, const void* l) {
    __builtin_amdgcn_global_load_lds(
        (__attribute__((address_space(1))) unsigned int*)(uintptr_t)g,
        (__attribute__((address_space(3))) unsigned int*)(unsigned int)(uintptr_t)l,
        16, 0, 0);
}

// ------------------------------- rope tables -------------------------------
__global__ void rope_tables_k(float* __restrict__ cosT, float* __restrict__ sinT) {
    int idx = blockIdx.x * 256 + threadIdx.x;   // 32768 = 1024*32
    int l = idx >> 5, d = idx & 31;
    double ang = (double)l * pow(500000.0, -(double)(2 * d) / 64.0);
    cosT[idx] = (float)cos(ang);
    sinT[idx] = (float)sin(ang);
}

// ------------------------------- embedding ---------------------------------
__global__ void embed_k(const int* __restrict__ ids, const float* __restrict__ emb,
                        float* __restrict__ h) {
    int tok = blockIdx.x;
    int id = ids[tok];
    ((float4*)(h + (size_t)tok * HIDDEN))[threadIdx.x] =
        ((const float4*)(emb + (size_t)id * HIDDEN))[threadIdx.x];
}

// ------------------------------- casts -------------------------------------
__global__ void cast_plain(const float* __restrict__ s, bf16* __restrict__ d, int n4) {
    int i = blockIdx.x * 256 + threadIdx.x;
    if (i >= n4) return;
    float4 v = ((const float4*)s)[i];
    BF4 u;
    u.h[0] = (bf16)v.x; u.h[1] = (bf16)v.y; u.h[2] = (bf16)v.z; u.h[3] = (bf16)v.w;
    ((short4*)d)[i] = u.p;
}

// gather (layers,R,K) f32 -> fused bf16 rows [i*dstStride + dstOff + r]
__global__ void cast_fuse(const float* __restrict__ s, bf16* __restrict__ d,
                          int R, int K4, int dstStride, int dstOff, int total4) {
    int idx = blockIdx.x * 256 + threadIdx.x;
    if (idx >= total4) return;
    int perLayer = R * K4;
    int i = idx / perLayer;
    int rem = idx - i * perLayer;
    int r = rem / K4, c4 = rem - r * K4;
    float4 v = ((const float4*)s)[idx];
    BF4 u;
    u.h[0] = (bf16)v.x; u.h[1] = (bf16)v.y; u.h[2] = (bf16)v.z; u.h[3] = (bf16)v.w;
    ((short4*)d)[((size_t)i * dstStride + dstOff + r) * K4 + c4] = u.p;
}

__global__ void cast_embed_pad(const float* __restrict__ s, bf16* __restrict__ d) {
    int i = blockIdx.x * 256 + threadIdx.x;   // 128*128 = 16384 short4s
    int row = i >> 7, c4 = i & 127;
    BF4 u;
    if (row < VOCN) {
        float4 v = ((const float4*)s)[row * 128 + c4];
        u.h[0] = (bf16)v.x; u.h[1] = (bf16)v.y; u.h[2] = (bf16)v.z; u.h[3] = (bf16)v.w;
    } else {
        u.h[0] = (bf16)0.f; u.h[1] = (bf16)0.f; u.h[2] = (bf16)0.f; u.h[3] = (bf16)0.f;
    }
    ((short4*)d)[i] = u.p;
}

// ------------------------------- rmsnorm -> bf16 ---------------------------
__global__ void rmsnorm512(const float* __restrict__ in, const float* __restrict__ w,
                           bf16* __restrict__ out) {
    int row = blockIdx.x, t = threadIdx.x;     // 128 threads
    float4 x = ((const float4*)(in + (size_t)row * 512))[t];
    float s = x.x * x.x + x.y * x.y + x.z * x.z + x.w * x.w;
    for (int m = 1; m < 64; m <<= 1) s += __shfl_xor(s, m);
    __shared__ float red[2];
    if ((t & 63) == 0) red[t >> 6] = s;
    __syncthreads();
    float tot = red[0] + red[1];
    float r = rsqrtf(tot * (1.f / 512.f) + 1e-6f);
    float4 wv = ((const float4*)w)[t];
    BF4 u;
    u.h[0] = (bf16)(x.x * r * wv.x); u.h[1] = (bf16)(x.y * r * wv.y);
    u.h[2] = (bf16)(x.z * r * wv.z); u.h[3] = (bf16)(x.w * r * wv.w);
    ((short4*)(out + (size_t)row * 512))[t] = u.p;
}

// ------------------------------- bf16 MFMA GEMM ----------------------------
// C = A(bf16, MxK rm) @ B(bf16, NxK rm)^T. 128x128 tile, Kstep 32, 4 waves.
// MODE 0: C(f32)=v  MODE 1: C(f32)+=v  MODE 3: Cb(bf16)=v
// stores bounded by col<Nreal with row stride Nreal.
template <int MODE>
__global__ __launch_bounds__(256) void gemm_bf16(const bf16* __restrict__ A,
                                                 const bf16* __restrict__ B,
                                                 float* __restrict__ C,
                                                 bf16* __restrict__ Cb,
                                                 int M, int N, int K, int Nreal) {
    __shared__ bf16 As[128 * 32];
    __shared__ bf16 Bs[128 * 32];
    const int tid = threadIdx.x;
    const int wave = tid >> 6, lane = tid & 63;
    const int row0 = blockIdx.y * 128, col0 = blockIdx.x * 128;
    floatx4 acc[4][4];
#pragma unroll
    for (int i = 0; i < 4; ++i)
#pragma unroll
        for (int j = 0; j < 4; ++j) acc[i][j] = (floatx4){0.f, 0.f, 0.f, 0.f};
    const int m0 = (wave & 1) * 64, n0 = (wave >> 1) * 64;
    const int sr = tid >> 2;            // staged row (issue 0)
    const int ske = (tid & 3) * 8;      // staged k element
    const size_t arow1 = (size_t)(row0 + sr) * K + ske;
    const size_t arow2 = (size_t)(row0 + 64 + sr) * K + ske;
    const size_t brow1 = (size_t)(col0 + sr) * K + ske;
    const size_t brow2 = (size_t)(col0 + 64 + sr) * K + ske;
    char* AsB = (char*)As;
    char* BsB = (char*)Bs;
    const int lds0 = wave * 1024, lds1 = 4096 + wave * 1024;

    for (int k0 = 0; k0 < K; k0 += 32) {
        gload16(A + arow1 + k0, AsB + lds0);
        gload16(A + arow2 + k0, AsB + lds1);
        gload16(B + brow1 + k0, BsB + lds0);
        gload16(B + brow2 + k0, BsB + lds1);
        __syncthreads();
        bf16x8 af[4], bfr[4];
#pragma unroll
        for (int mi = 0; mi < 4; ++mi)
            af[mi] = *(const bf16x8*)(AsB + ((m0 + mi * 16 + (lane & 15)) * 32 + (lane >> 4) * 8) * 2);
#pragma unroll
        for (int ni = 0; ni < 4; ++ni)
            bfr[ni] = *(const bf16x8*)(BsB + ((n0 + ni * 16 + (lane & 15)) * 32 + (lane >> 4) * 8) * 2);
#pragma unroll
        for (int mi = 0; mi < 4; ++mi)
#pragma unroll
            for (int ni = 0; ni < 4; ++ni)
                acc[mi][ni] = __builtin_amdgcn_mfma_f32_16x16x32_bf16(af[mi], bfr[ni], acc[mi][ni], 0, 0, 0);
        __syncthreads();
    }
    const int cr = (lane >> 4) * 4;
    const int cc = lane & 15;
#pragma unroll
    for (int mi = 0; mi < 4; ++mi) {
#pragma unroll
        for (int ni = 0; ni < 4; ++ni) {
#pragma unroll
            for (int r = 0; r < 4; ++r) {
                int row = row0 + m0 + mi * 16 + cr + r;
                int col = col0 + n0 + ni * 16 + cc;
                if (col < Nreal) {
                    size_t o = (size_t)row * Nreal + col;
                    float v = acc[mi][ni][r];
                    if (MODE == 0) C[o] = v;
                    else if (MODE == 1) C[o] += v;
                    else if (MODE == 3) Cb[o] = (bf16)v;
                }
            }
        }
    }
}

// ------------------------------- RoPE (fused QKV, stride 1536) -------------
__global__ void rope_apply(float* __restrict__ P, const float* __restrict__ cosT,
                           const float* __restrict__ sinT) {
    int tok = blockIdx.x;
    int l = tok & (LSEQ - 1);
    int hh = threadIdx.x >> 5, d = threadIdx.x & 31;   // 8 heads x 32 pairs
    float c = cosT[l * 32 + d], s = sinT[l * 32 + d];
    float* q = P + (size_t)tok * 1536 + hh * HDIM;
    float* k = q + 512;
    float q1 = q[d], q2 = q[d + 32];
    q[d] = q1 * c - q2 * s;
    q[d + 32] = q2 * c + q1 * s;
    float k1 = k[d], k2 = k[d + 32];
    k[d] = k1 * c - k2 * s;
    k[d + 32] = k2 * c + k1 * s;
}

// ------------------------------- attention ---------------------------------
// fused QKV input (stride 1536: q@0, k@512, v@1024), bf16 output (stride 512).
__global__ __launch_bounds__(256) void attn_k(const float* __restrict__ P,
                                              bf16* __restrict__ O) {
    int t = blockIdx.x, hh = blockIdx.y, b = blockIdx.z;
    int l0 = t * 8;
    __shared__ __align__(16) float sc[8][1032];   // stride%32==8 -> 2-way (free)
    __shared__ __align__(16) float qt[8][64];
    __shared__ float red[8][32];
    __shared__ float rowm[8], rows[8];

    if (threadIdx.x < 128) {
        int e = threadIdx.x;
        int r = e >> 4, d4 = e & 15;
        *(float4*)&qt[r][d4 * 4] =
            *(const float4*)(P + (size_t)(b * LSEQ + l0 + r) * 1536 + hh * HDIM + d4 * 4);
    }
    __syncthreads();
    int r = threadIdx.x & 7, c = threadIdx.x >> 3;  // c in 0..31
    int jmax = l0 + r;
    for (int j = c; j < l0 + 8; j += 32) {
        if (j <= jmax) {
            const float4* kp = (const float4*)(P + (size_t)(b * LSEQ + j) * 1536 + 512 + hh * HDIM);
            float s = 0.f;
#pragma unroll
            for (int d4 = 0; d4 < 16; ++d4) {
                float4 kv = kp[d4];
                float4 qv = *(const float4*)&qt[r][d4 * 4];
                s += qv.x * kv.x + qv.y * kv.y + qv.z * kv.z + qv.w * kv.w;
            }
            sc[r][j] = s * 0.125f;
        }
    }
    __syncthreads();
    float m = -1e30f;
    for (int j = c; j <= jmax; j += 32) m = fmaxf(m, sc[r][j]);
    red[r][c] = m;
    __syncthreads();
    if (c == 0) {
        float mm = -1e30f;
        for (int x = 0; x < 32; ++x) mm = fmaxf(mm, red[r][x]);
        rowm[r] = mm;
    }
    __syncthreads();
    float mrow = rowm[r];
    float sum = 0.f;
    for (int j = c; j <= jmax; j += 32) {
        float e = __expf(sc[r][j] - mrow);
        sc[r][j] = e;
        sum += e;
    }
    red[r][c] = sum;
    __syncthreads();
    if (c == 0) {
        float ss = 0.f;
        for (int x = 0; x < 32; ++x) ss += red[r][x];
        rows[r] = ss;
    }
    __syncthreads();
    float inv = 1.f / rows[r];
    float ax = 0.f, ay = 0.f;
    const float* vbase = P + (size_t)(b * LSEQ) * 1536 + 1024 + hh * HDIM + c * 2;
    for (int j = 0; j <= jmax; ++j) {
        float p = sc[r][j];
        float2 vv = *(const float2*)(vbase + (size_t)j * 1536);
        ax += p * vv.x;
        ay += p * vv.y;
    }
    BF2 o;
    o.h[0] = (bf16)(ax * inv);
    o.h[1] = (bf16)(ay * inv);
    *(unsigned*)(O + (size_t)(b * LSEQ + l0 + r) * 512 + hh * HDIM + c * 2) = o.u;
}

// ------------------------------- delta scan --------------------------------
// fused proj input P (stride 1536: k@0,v@256,q@512,b@768,a@1024).
__global__ __launch_bounds__(1024) void delta_scan(
    const float* __restrict__ P, const float* __restrict__ S_in,
    const float* __restrict__ bbias, const float* __restrict__ abias,
    float* __restrict__ S_out, float* __restrict__ ctx) {
    int b = blockIdx.x >> 3, hh = blockIdx.x & 7;
    int i = threadIdx.x >> 5, j = threadIdx.x & 31;
    float S = S_in[((size_t)(b * SHEAD + hh) * SDHD + i) * SDHD + j];
    __shared__ float ks[64][33], vs[64][33], qs[64][33], bs[64][33], as_[64][33];
    __shared__ float rn[64];
    for (int c0 = 0; c0 < LSEQ; c0 += 64) {
        __syncthreads();
        for (int e = threadIdx.x; e < 2048; e += 1024) {
            int l = e >> 5, jj = e & 31;
            size_t g = (size_t)(b * LSEQ + c0 + l) * 1536 + hh * SDHD + jj;
            ks[l][jj] = P[g];
            vs[l][jj] = P[g + 256];
            qs[l][jj] = P[g + 512];
            bs[l][jj] = 1.f / (1.f + __expf(-(P[g + 768] + bbias[hh * SDHD + jj])));
            as_[l][jj] = 1.f / (1.f + __expf(-(P[g + 1024] + abias[hh * SDHD + jj])));
        }
        __syncthreads();
        if (threadIdx.x < 64) {
            int l = threadIdx.x;
            float s = 0.f;
#pragma unroll
            for (int x = 0; x < 32; ++x) {
                float kv = ks[l][x];
                s += kv * kv;
            }
            rn[l] = 1.f / fmaxf(sqrtf(s), 1e-12f);
        }
        __syncthreads();
        for (int lc = 0; lc < 64; ++lc) {
            float kj = ks[lc][j] * rn[lc];
            float ai = as_[lc][i], bi = bs[lc][i], vi = vs[lc][i], qj = qs[lc][j];
            S *= ai;
            float p = S * kj;
            p += __shfl_xor(p, 1);
            p += __shfl_xor(p, 2);
            p += __shfl_xor(p, 4);
            p += __shfl_xor(p, 8);
            p += __shfl_xor(p, 16);
            S += bi * (vi - p) * kj;
            float rd = S * qj;
            rd += __shfl_xor(rd, 1);
            rd += __shfl_xor(rd, 2);
            rd += __shfl_xor(rd, 4);
            rd += __shfl_xor(rd, 8);
            rd += __shfl_xor(rd, 16);
            if (j == 0) ctx[(size_t)(b * LSEQ + c0 + lc) * SDIMM + hh * SDHD + i] = rd;
        }
    }
    S_out[((size_t)(b * SHEAD + hh) * SDHD + i) * SDHD + j] = S;
}

// ------------- ctxbf = bf16(rmsnorm(ctx,nw)*silu(gate)), gate in P@1280 ----
__global__ void ctx_post(const float* __restrict__ ctx, const float* __restrict__ P,
                         const float* __restrict__ nw, bf16* __restrict__ out) {
    int row = blockIdx.x, t = threadIdx.x;  // 64 threads
    float4 x = ((const float4*)(ctx + (size_t)row * SDIMM))[t];
    float s = x.x * x.x + x.y * x.y + x.z * x.z + x.w * x.w;
    for (int m = 1; m < 64; m <<= 1) s += __shfl_xor(s, m);
    float r = rsqrtf(s * (1.f / 256.f) + 1e-6f);
    float4 n = ((const float4*)nw)[t];
    float4 g = ((const float4*)(P + (size_t)row * 1536 + 1280))[t];
    BF4 u;
    u.h[0] = (bf16)(x.x * r * n.x * (g.x / (1.f + __expf(-g.x))));
    u.h[1] = (bf16)(x.y * r * n.y * (g.y / (1.f + __expf(-g.y))));
    u.h[2] = (bf16)(x.z * r * n.z * (g.z / (1.f + __expf(-g.z))));
    u.h[3] = (bf16)(x.w * r * n.w * (g.w / (1.f + __expf(-g.w))));
    ((short4*)(out + (size_t)row * SDIMM))[t] = u.p;
}

// --------------- a1b = bf16(silu(gu[:, :1536]) * gu[:, 1536:]) -------------
__global__ void silu_mul_k(const bf16* __restrict__ gu, bf16* __restrict__ o, int total4) {
    int i = blockIdx.x * 256 + threadIdx.x;   // total4 = 4096*1536/4
    if (i >= total4) return;
    int tok = i / 384, c4 = i - tok * 384;
    BF4 gb, ub, ob;
    gb.p = ((const short4*)(gu + (size_t)tok * 3072))[c4];
    ub.p = ((const short4*)(gu + (size_t)tok * 3072 + 1536))[c4];
#pragma unroll
    for (int e = 0; e < 4; ++e) {
        float g = (float)gb.h[e], u = (float)ub.h[e];
        ob.h[e] = (bf16)(g / (1.f + __expf(-g)) * u);
    }
    ((short4*)o)[i] = ob.p;
}

// ---------------------------------------------------------------------------
extern "C" void kernel_launch(void* const* d_in, const int* in_sizes, int n_in,
                              void* d_out, int out_size, void* d_ws, size_t ws_size,
                              hipStream_t stream) {
    (void)in_sizes; (void)n_in; (void)out_size; (void)ws_size;
    const int* ids = (const int*)d_in[0];
    const float* state = (const float*)d_in[1];
    const float* embedw = (const float*)d_in[2];
    auto F = [&](int i) { return (const float*)d_in[i]; };

    char* wsb = (char*)d_ws;
    const size_t MB = 1048576;
    float* H    = (float*)(wsb);                 // 8 MB
    bf16*  XNbf = (bf16*)(wsb + 8 * MB);         // 4 MB
    bf16*  Hbf  = (bf16*)(wsb + 12 * MB);        // 4 MB
    float* P    = (float*)(wsb + 16 * MB);       // 24 MB (QKV f32 / delta f32 / GU bf16)
    bf16*  Pbf  = (bf16*)P;
    bf16*  Obf  = (bf16*)(wsb + 40 * MB);        // 12 MB (attn out 4MB, then A1b)
    bf16*  A1b  = Obf;
    float* ctxf = (float*)(wsb + 52 * MB);       // 4 MB
    bf16*  ctxb = (bf16*)(wsb + 56 * MB);        // 2 MB
    float* cosT = (float*)(wsb + 58 * MB);
    float* sinT = cosT + 32768;
    float* Sbuf = sinT + 32768;                  // 128 KB
    char*  wbase = wsb + 59 * MB;
    bf16* wqkv  = (bf16*)(wbase);                        // 6x1536x512
    bf16* wob   = (bf16*)(wbase + 9437184);              // 6x512x512
    bf16* wgu   = (bf16*)(wbase + 12582912);             // 6x3072x512
    bf16* wdnb  = (bf16*)(wbase + 31457280);             // 6x512x1536
    bf16* wdR   = (bf16*)(wbase + 40894464);             // 1536x512
    bf16* woutR = (bf16*)(wbase + 42467328);             // 512x256
    bf16* wdW   = (bf16*)(wbase + 42729472);             // 1536x512
    bf16* woutW = (bf16*)(wbase + 44302336);             // 512x256
    bf16* embp  = (bf16*)(wbase + 44564480);             // 128x512 padded

    float* out = (float*)d_out;
    float* logits = out;                // 4096x63
    float* Sout = out + 4096 * VOCN;    // 32768

    auto G = [&](int mode, const bf16* A, const bf16* B, float* C, bf16* Cb,
                 int M, int N, int K, int Nreal) {
        dim3 grid(N / 128, M / 128);
        if (mode == 0) gemm_bf16<0><<<grid, 256, 0, stream>>>(A, B, C, Cb, M, N, K, Nreal);
        else if (mode == 1) gemm_bf16<1><<<grid, 256, 0, stream>>>(A, B, C, Cb, M, N, K, Nreal);
        else gemm_bf16<3><<<grid, 256, 0, stream>>>(A, B, C, Cb, M, N, K, Nreal);
    };
    auto CP = [&](const float* s, bf16* d, int n4) {
        cast_plain<<<(n4 + 255) / 256, 256, 0, stream>>>(s, d, n4);
    };

    // ---- weight casts ----
    cast_fuse<<<1536, 256, 0, stream>>>(F(24), wqkv, 512, 128, 1536, 0, 393216);
    cast_fuse<<<1536, 256, 0, stream>>>(F(25), wqkv, 512, 128, 1536, 512, 393216);
    cast_fuse<<<1536, 256, 0, stream>>>(F(26), wqkv, 512, 128, 1536, 1024, 393216);
    CP(F(27), wob, 393216);
    cast_fuse<<<4608, 256, 0, stream>>>(F(29), wgu, 1536, 128, 3072, 0, 1179648);
    cast_fuse<<<4608, 256, 0, stream>>>(F(30), wgu, 1536, 128, 3072, 1536, 1179648);
    CP(F(31), wdnb, 1179648);
    CP(F(3), wdR, 32768);  CP(F(4), wdR + 256 * 512, 32768);
    CP(F(5), wdR + 512 * 512, 32768); CP(F(6), wdR + 768 * 512, 32768);
    CP(F(8), wdR + 1024 * 512, 32768); CP(F(12), wdR + 1280 * 512, 32768);
    CP(F(10), woutR, 32768);
    CP(F(13), wdW, 32768); CP(F(14), wdW + 256 * 512, 32768);
    CP(F(15), wdW + 512 * 512, 32768); CP(F(16), wdW + 768 * 512, 32768);
    CP(F(18), wdW + 1024 * 512, 32768); CP(F(22), wdW + 1280 * 512, 32768);
    CP(F(20), woutW, 32768);
    cast_embed_pad<<<64, 256, 0, stream>>>(embedw, embp);

    rope_tables_k<<<128, 256, 0, stream>>>(cosT, sinT);
    embed_k<<<4096, 128, 0, stream>>>(ids, embedw, H);

    // ---- delta read ----
    CP(H, Hbf, 524288);
    G(0, Hbf, wdR, P, nullptr, 4096, 1536, 512, 1536);
    delta_scan<<<32, 1024, 0, stream>>>(P, state, F(7), F(9), Sbuf, ctxf);
    ctx_post<<<4096, 64, 0, stream>>>(ctxf, P, F(11), ctxb);
    G(1, ctxb, woutR, H, nullptr, 4096, 512, 256, 512);

    for (int i = 0; i < 6; ++i) {
        rmsnorm512<<<4096, 128, 0, stream>>>(H, F(23) + (size_t)i * 512, XNbf);
        G(0, XNbf, wqkv + (size_t)i * 1536 * 512, P, nullptr, 4096, 1536, 512, 1536);
        rope_apply<<<4096, 256, 0, stream>>>(P, cosT, sinT);
        attn_k<<<dim3(128, 8, 4), 256, 0, stream>>>(P, Obf);
        G(1, Obf, wob + (size_t)i * 512 * 512, H, nullptr, 4096, 512, 512, 512);
        rmsnorm512<<<4096, 128, 0, stream>>>(H, F(28) + (size_t)i * 512, XNbf);
        G(3, XNbf, wgu + (size_t)i * 3072 * 512, nullptr, Pbf, 4096, 3072, 512, 3072);
        silu_mul_k<<<6144, 256, 0, stream>>>(Pbf, A1b, 1572864);
        G(1, A1b, wdnb + (size_t)i * 512 * 1536, H, nullptr, 4096, 512, 1536, 512);
    }

    // ---- delta write ----
    CP(H, Hbf, 524288);
    G(0, Hbf, wdW, P, nullptr, 4096, 1536, 512, 1536);
    delta_scan<<<32, 1024, 0, stream>>>(P, Sbuf, F(17), F(19), Sout, ctxf);
    ctx_post<<<4096, 64, 0, stream>>>(ctxf, P, F(21), ctxb);
    G(1, ctxb, woutW, H, nullptr, 4096, 512, 256, 512);

    rmsnorm512<<<4096, 128, 0, stream>>>(H, F(32), XNbf);
    G(0, XNbf, embp, logits, nullptr, 4096, 128, 512, VOCN);
}

// Round 3
// 2501.612 us; speedup vs baseline: 5.0752x; 2.1386x over previous
//
#include <hip/hip_runtime.h>
#include <hip/hip_bf16.h>
#include <math.h>

// ---------------------------------------------------------------------------
// BashTransformer forward on MI355X. Round 3: MFMA flash attention (bf16),
// bf16 MFMA GEMMs (m97 structure), fused QKV / gate-up / delta projections.
// ---------------------------------------------------------------------------

#define LSEQ 1024
#define BATCH 4
#define HIDDEN 512
#define NHEAD 8
#define HDIM 64
#define SHEAD 8
#define SDHD 32
#define SDIMM 256
#define FFND 1536
#define VOCN 63
#define ATTS 72   // LDS row stride (elems): 144B = 16B-aligned, 2-way banks (free)

typedef __bf16 bf16;
typedef __attribute__((ext_vector_type(8))) __bf16 bf16x8;
typedef __attribute__((ext_vector_type(4))) float floatx4;

union BF4 { bf16 h[4]; short4 p; };

__device__ __forceinline__ void gload16(const void* g, const void* l) {
    __builtin_amdgcn_global_load_lds(
        (__attribute__((address_space(1))) unsigned int*)(uintptr_t)g,
        (__attribute__((address_space(3))) unsigned int*)(unsigned int)(uintptr_t)l,
        16, 0, 0);
}

// ------------------------------- rope tables -------------------------------
__global__ void rope_tables_k(float* __restrict__ cosT, float* __restrict__ sinT) {
    int idx = blockIdx.x * 256 + threadIdx.x;   // 32768 = 1024*32
    int l = idx >> 5, d = idx & 31;
    double ang = (double)l * pow(500000.0, -(double)(2 * d) / 64.0);
    cosT[idx] = (float)cos(ang);
    sinT[idx] = (float)sin(ang);
}

// ------------------------------- embedding ---------------------------------
__global__ void embed_k(const int* __restrict__ ids, const float* __restrict__ emb,
                        float* __restrict__ h) {
    int tok = blockIdx.x;
    int id = ids[tok];
    ((float4*)(h + (size_t)tok * HIDDEN))[threadIdx.x] =
        ((const float4*)(emb + (size_t)id * HIDDEN))[threadIdx.x];
}

// ------------------------------- casts -------------------------------------
__global__ void cast_plain(const float* __restrict__ s, bf16* __restrict__ d, int n4) {
    int i = blockIdx.x * 256 + threadIdx.x;
    if (i >= n4) return;
    float4 v = ((const float4*)s)[i];
    BF4 u;
    u.h[0] = (bf16)v.x; u.h[1] = (bf16)v.y; u.h[2] = (bf16)v.z; u.h[3] = (bf16)v.w;
    ((short4*)d)[i] = u.p;
}

// six 256x512 f32 matrices -> one fused 1536x512 bf16 (order s0..s5)
__global__ void cast6(const float* s0, const float* s1, const float* s2,
                      const float* s3, const float* s4, const float* s5,
                      bf16* __restrict__ d) {
    int i = blockIdx.x * 256 + threadIdx.x;      // 196608 short4s
    if (i >= 196608) return;
    int which = i >> 15, loc = i & 32767;
    const float* s = which == 0 ? s0 : which == 1 ? s1 : which == 2 ? s2
                    : which == 3 ? s3 : which == 4 ? s4 : s5;
    float4 v = ((const float4*)s)[loc];
    BF4 u;
    u.h[0] = (bf16)v.x; u.h[1] = (bf16)v.y; u.h[2] = (bf16)v.z; u.h[3] = (bf16)v.w;
    ((short4*)d)[i] = u.p;
}

// gather (layers,R,K) f32 -> fused bf16 rows [i*dstStride + dstOff + r]
__global__ void cast_fuse(const float* __restrict__ s, bf16* __restrict__ d,
                          int R, int K4, int dstStride, int dstOff, int total4) {
    int idx = blockIdx.x * 256 + threadIdx.x;
    if (idx >= total4) return;
    int perLayer = R * K4;
    int i = idx / perLayer;
    int rem = idx - i * perLayer;
    int r = rem / K4, c4 = rem - r * K4;
    float4 v = ((const float4*)s)[idx];
    BF4 u;
    u.h[0] = (bf16)v.x; u.h[1] = (bf16)v.y; u.h[2] = (bf16)v.z; u.h[3] = (bf16)v.w;
    ((short4*)d)[((size_t)i * dstStride + dstOff + r) * K4 + c4] = u.p;
}

__global__ void cast_embed_pad(const float* __restrict__ s, bf16* __restrict__ d) {
    int i = blockIdx.x * 256 + threadIdx.x;   // 128*128 = 16384 short4s
    int row = i >> 7, c4 = i & 127;
    BF4 u;
    if (row < VOCN) {
        float4 v = ((const float4*)s)[row * 128 + c4];
        u.h[0] = (bf16)v.x; u.h[1] = (bf16)v.y; u.h[2] = (bf16)v.z; u.h[3] = (bf16)v.w;
    } else {
        u.h[0] = (bf16)0.f; u.h[1] = (bf16)0.f; u.h[2] = (bf16)0.f; u.h[3] = (bf16)0.f;
    }
    ((short4*)d)[i] = u.p;
}

// ------------------------------- rmsnorm -> bf16 ---------------------------
__global__ void rmsnorm512(const float* __restrict__ in, const float* __restrict__ w,
                           bf16* __restrict__ out) {
    int row = blockIdx.x, t = threadIdx.x;     // 128 threads
    float4 x = ((const float4*)(in + (size_t)row * 512))[t];
    float s = x.x * x.x + x.y * x.y + x.z * x.z + x.w * x.w;
    for (int m = 1; m < 64; m <<= 1) s += __shfl_xor(s, m);
    __shared__ float red[2];
    if ((t & 63) == 0) red[t >> 6] = s;
    __syncthreads();
    float tot = red[0] + red[1];
    float r = rsqrtf(tot * (1.f / 512.f) + 1e-6f);
    float4 wv = ((const float4*)w)[t];
    BF4 u;
    u.h[0] = (bf16)(x.x * r * wv.x); u.h[1] = (bf16)(x.y * r * wv.y);
    u.h[2] = (bf16)(x.z * r * wv.z); u.h[3] = (bf16)(x.w * r * wv.w);
    ((short4*)(out + (size_t)row * 512))[t] = u.p;
}

// ------------------------------- bf16 MFMA GEMM ----------------------------
// C = A(bf16, MxK rm) @ B(bf16, NxK rm)^T. 128x128 tile, Kstep 32, 4 waves.
// MODE 0: C(f32)=v  MODE 1: C(f32)+=v  MODE 3: Cb(bf16)=v
template <int MODE>
__global__ __launch_bounds__(256) void gemm_bf16(const bf16* __restrict__ A,
                                                 const bf16* __restrict__ B,
                                                 float* __restrict__ C,
                                                 bf16* __restrict__ Cb,
                                                 int M, int N, int K, int Nreal) {
    __shared__ bf16 As[128 * 32];
    __shared__ bf16 Bs[128 * 32];
    const int tid = threadIdx.x;
    const int wave = tid >> 6, lane = tid & 63;
    const int row0 = blockIdx.y * 128, col0 = blockIdx.x * 128;
    floatx4 acc[4][4];
#pragma unroll
    for (int i = 0; i < 4; ++i)
#pragma unroll
        for (int j = 0; j < 4; ++j) acc[i][j] = (floatx4){0.f, 0.f, 0.f, 0.f};
    const int m0 = (wave & 1) * 64, n0 = (wave >> 1) * 64;
    const int sr = tid >> 2;
    const int ske = (tid & 3) * 8;
    const size_t arow1 = (size_t)(row0 + sr) * K + ske;
    const size_t arow2 = (size_t)(row0 + 64 + sr) * K + ske;
    const size_t brow1 = (size_t)(col0 + sr) * K + ske;
    const size_t brow2 = (size_t)(col0 + 64 + sr) * K + ske;
    char* AsB = (char*)As;
    char* BsB = (char*)Bs;
    const int lds0 = wave * 1024, lds1 = 4096 + wave * 1024;

    for (int k0 = 0; k0 < K; k0 += 32) {
        gload16(A + arow1 + k0, AsB + lds0);
        gload16(A + arow2 + k0, AsB + lds1);
        gload16(B + brow1 + k0, BsB + lds0);
        gload16(B + brow2 + k0, BsB + lds1);
        __syncthreads();
        bf16x8 af[4], bfr[4];
#pragma unroll
        for (int mi = 0; mi < 4; ++mi)
            af[mi] = *(const bf16x8*)(AsB + ((m0 + mi * 16 + (lane & 15)) * 32 + (lane >> 4) * 8) * 2);
#pragma unroll
        for (int ni = 0; ni < 4; ++ni)
            bfr[ni] = *(const bf16x8*)(BsB + ((n0 + ni * 16 + (lane & 15)) * 32 + (lane >> 4) * 8) * 2);
#pragma unroll
        for (int mi = 0; mi < 4; ++mi)
#pragma unroll
            for (int ni = 0; ni < 4; ++ni)
                acc[mi][ni] = __builtin_amdgcn_mfma_f32_16x16x32_bf16(af[mi], bfr[ni], acc[mi][ni], 0, 0, 0);
        __syncthreads();
    }
    const int cr = (lane >> 4) * 4;
    const int cc = lane & 15;
#pragma unroll
    for (int mi = 0; mi < 4; ++mi) {
#pragma unroll
        for (int ni = 0; ni < 4; ++ni) {
#pragma unroll
            for (int r = 0; r < 4; ++r) {
                int row = row0 + m0 + mi * 16 + cr + r;
                int col = col0 + n0 + ni * 16 + cc;
                if (col < Nreal) {
                    size_t o = (size_t)row * Nreal + col;
                    float v = acc[mi][ni][r];
                    if (MODE == 0) C[o] = v;
                    else if (MODE == 1) C[o] += v;
                    else if (MODE == 3) Cb[o] = (bf16)v;
                }
            }
        }
    }
}

// ----------------- QKV prep: RoPE + bf16 cast + V transpose ----------------
// P fused (stride 1536: q@0,k@512,v@1024) -> Qb,Kb [bh][l][64], Vtb [bh][64][l]
__global__ void qkv_prep(const float* __restrict__ P, const float* __restrict__ cosT,
                         const float* __restrict__ sinT, bf16* __restrict__ Qb,
                         bf16* __restrict__ Kb, bf16* __restrict__ Vtb) {
    int tok = blockIdx.x;                       // 4096
    int b = tok >> 10, l = tok & 1023;
    int hh = threadIdx.x >> 5, d = threadIdx.x & 31;
    const float* q = P + (size_t)tok * 1536 + hh * 64;
    const float* k = q + 512;
    const float* v = q + 1024;
    float c = cosT[l * 32 + d], s = sinT[l * 32 + d];
    size_t base = ((size_t)(b * 8 + hh) * 1024 + l) * 64;
    float q1 = q[d], q2 = q[d + 32];
    Qb[base + d] = (bf16)(q1 * c - q2 * s);
    Qb[base + d + 32] = (bf16)(q2 * c + q1 * s);
    float k1 = k[d], k2 = k[d + 32];
    Kb[base + d] = (bf16)(k1 * c - k2 * s);
    Kb[base + d + 32] = (bf16)(k2 * c + k1 * s);
    size_t vb = (size_t)(b * 8 + hh) * 64 * 1024 + l;
    Vtb[vb + (size_t)d * 1024] = (bf16)v[d];
    Vtb[vb + (size_t)(d + 32) * 1024] = (bf16)v[d + 32];
}

// ------------------------- MFMA flash attention ----------------------------
// grid (16 qtiles, 8 h, 4 b), 256 threads = 4 waves x 16 q-rows.
__global__ __launch_bounds__(256) void attn_mfma(const bf16* __restrict__ Qb,
                                                 const bf16* __restrict__ Kb,
                                                 const bf16* __restrict__ Vtb,
                                                 bf16* __restrict__ O) {
    int qt = blockIdx.x, hh = blockIdx.y, b = blockIdx.z;
    int bh = b * 8 + hh;
    int q0 = qt * 64;
    const bf16* Qg = Qb + ((size_t)bh * 1024 + q0) * 64;
    const bf16* Kg = Kb + (size_t)bh * 1024 * 64;
    const bf16* Vg = Vtb + (size_t)bh * 64 * 1024;   // [64 d][1024 l]
    __shared__ bf16 Qs[64 * ATTS];
    __shared__ bf16 Ks[64 * ATTS];
    __shared__ bf16 Vs[64 * ATTS];
    __shared__ bf16 Ps[64 * ATTS];
    int tid = threadIdx.x, wave = tid >> 6, lane = tid & 63;
    int lr = lane & 15, quad = lane >> 4;

    // stage Q once
#pragma unroll
    for (int it = 0; it < 2; ++it) {
        int cidx = tid + it * 256;
        int row = cidx >> 3, ch = cidx & 7;
        *(bf16x8*)(Qs + row * ATTS + ch * 8) = *(const bf16x8*)(Qg + row * 64 + ch * 8);
    }
    float mrow[4], lrow[4];
    floatx4 Oacc[4];
#pragma unroll
    for (int r = 0; r < 4; ++r) { mrow[r] = -1e30f; lrow[r] = 0.f; }
#pragma unroll
    for (int d0 = 0; d0 < 4; ++d0) Oacc[d0] = (floatx4){0.f, 0.f, 0.f, 0.f};

    int ntiles = qt + 1;
    for (int t = 0; t < ntiles; ++t) {
        int kv0 = t * 64;
        __syncthreads();
#pragma unroll
        for (int it = 0; it < 2; ++it) {
            int cidx = tid + it * 256;
            int row = cidx >> 3, ch = cidx & 7;
            *(bf16x8*)(Ks + row * ATTS + ch * 8) =
                *(const bf16x8*)(Kg + (size_t)(kv0 + row) * 64 + ch * 8);
            *(bf16x8*)(Vs + row * ATTS + ch * 8) =
                *(const bf16x8*)(Vg + (size_t)row * 1024 + kv0 + ch * 8);
        }
        __syncthreads();
        // ---- S = Q K^T (wave's 16 rows x 64 cols) ----
        bf16x8 aq[2];
#pragma unroll
        for (int kc = 0; kc < 2; ++kc)
            aq[kc] = *(const bf16x8*)(Qs + (wave * 16 + lr) * ATTS + kc * 32 + quad * 8);
        floatx4 sacc[4];
#pragma unroll
        for (int n0 = 0; n0 < 4; ++n0) {
            bf16x8 bk0 = *(const bf16x8*)(Ks + (n0 * 16 + lr) * ATTS + quad * 8);
            bf16x8 bk1 = *(const bf16x8*)(Ks + (n0 * 16 + lr) * ATTS + 32 + quad * 8);
            floatx4 z = (floatx4){0.f, 0.f, 0.f, 0.f};
            z = __builtin_amdgcn_mfma_f32_16x16x32_bf16(aq[0], bk0, z, 0, 0, 0);
            sacc[n0] = __builtin_amdgcn_mfma_f32_16x16x32_bf16(aq[1], bk1, z, 0, 0, 0);
        }
        float sv[4][4];
#pragma unroll
        for (int n0 = 0; n0 < 4; ++n0)
#pragma unroll
            for (int r = 0; r < 4; ++r) sv[n0][r] = sacc[n0][r] * 0.125f;
        if (t == ntiles - 1) {   // diagonal tile mask: col > row
#pragma unroll
            for (int n0 = 0; n0 < 4; ++n0)
#pragma unroll
                for (int r = 0; r < 4; ++r)
                    if (n0 * 16 + lr > wave * 16 + quad * 4 + r) sv[n0][r] = -1e30f;
        }
        // ---- online softmax ----
        float al[4];
#pragma unroll
        for (int r = 0; r < 4; ++r) {
            float tm = fmaxf(fmaxf(sv[0][r], sv[1][r]), fmaxf(sv[2][r], sv[3][r]));
            tm = fmaxf(tm, __shfl_xor(tm, 1));
            tm = fmaxf(tm, __shfl_xor(tm, 2));
            tm = fmaxf(tm, __shfl_xor(tm, 4));
            tm = fmaxf(tm, __shfl_xor(tm, 8));
            float mn = fmaxf(mrow[r], tm);
            al[r] = __expf(mrow[r] - mn);
            mrow[r] = mn;
        }
        float rs[4];
#pragma unroll
        for (int r = 0; r < 4; ++r) rs[r] = 0.f;
#pragma unroll
        for (int n0 = 0; n0 < 4; ++n0)
#pragma unroll
            for (int r = 0; r < 4; ++r) {
                float p = __expf(sv[n0][r] - mrow[r]);
                sv[n0][r] = p;
                rs[r] += p;
            }
#pragma unroll
        for (int r = 0; r < 4; ++r) {
            float t2 = rs[r];
            t2 += __shfl_xor(t2, 1);
            t2 += __shfl_xor(t2, 2);
            t2 += __shfl_xor(t2, 4);
            t2 += __shfl_xor(t2, 8);
            lrow[r] = lrow[r] * al[r] + t2;
        }
#pragma unroll
        for (int d0 = 0; d0 < 4; ++d0)
#pragma unroll
            for (int r = 0; r < 4; ++r) Oacc[d0][r] *= al[r];
        // ---- P -> LDS (wave-private 16x64 slice) ----
#pragma unroll
        for (int n0 = 0; n0 < 4; ++n0)
#pragma unroll
            for (int r = 0; r < 4; ++r)
                Ps[(wave * 16 + quad * 4 + r) * ATTS + n0 * 16 + lr] = (bf16)sv[n0][r];
        // ---- O += P V ----
        bf16x8 ap[2];
#pragma unroll
        for (int kc = 0; kc < 2; ++kc)
            ap[kc] = *(const bf16x8*)(Ps + (wave * 16 + lr) * ATTS + kc * 32 + quad * 8);
#pragma unroll
        for (int d0 = 0; d0 < 4; ++d0) {
            bf16x8 bv0 = *(const bf16x8*)(Vs + (d0 * 16 + lr) * ATTS + quad * 8);
            bf16x8 bv1 = *(const bf16x8*)(Vs + (d0 * 16 + lr) * ATTS + 32 + quad * 8);
            Oacc[d0] = __builtin_amdgcn_mfma_f32_16x16x32_bf16(ap[0], bv0, Oacc[d0], 0, 0, 0);
            Oacc[d0] = __builtin_amdgcn_mfma_f32_16x16x32_bf16(ap[1], bv1, Oacc[d0], 0, 0, 0);
        }
    }
    // ---- epilogue ----
    float inv[4];
#pragma unroll
    for (int r = 0; r < 4; ++r) inv[r] = 1.f / lrow[r];
#pragma unroll
    for (int d0 = 0; d0 < 4; ++d0)
#pragma unroll
        for (int r = 0; r < 4; ++r) {
            int row = b * 1024 + q0 + wave * 16 + quad * 4 + r;
            int col = hh * 64 + d0 * 16 + lr;
            O[(size_t)row * 512 + col] = (bf16)(Oacc[d0][r] * inv[r]);
        }
}

// ------------------------------- delta scan --------------------------------
__global__ __launch_bounds__(1024) void delta_scan(
    const float* __restrict__ P, const float* __restrict__ S_in,
    const float* __restrict__ bbias, const float* __restrict__ abias,
    float* __restrict__ S_out, float* __restrict__ ctx) {
    int b = blockIdx.x >> 3, hh = blockIdx.x & 7;
    int i = threadIdx.x >> 5, j = threadIdx.x & 31;
    float S = S_in[((size_t)(b * SHEAD + hh) * SDHD + i) * SDHD + j];
    __shared__ float ks[64][33], vs[64][33], qs[64][33], bs[64][33], as_[64][33];
    __shared__ float rn[64];
    for (int c0 = 0; c0 < LSEQ; c0 += 64) {
        __syncthreads();
        for (int e = threadIdx.x; e < 2048; e += 1024) {
            int l = e >> 5, jj = e & 31;
            size_t g = (size_t)(b * LSEQ + c0 + l) * 1536 + hh * SDHD + jj;
            ks[l][jj] = P[g];
            vs[l][jj] = P[g + 256];
            qs[l][jj] = P[g + 512];
            bs[l][jj] = 1.f / (1.f + __expf(-(P[g + 768] + bbias[hh * SDHD + jj])));
            as_[l][jj] = 1.f / (1.f + __expf(-(P[g + 1024] + abias[hh * SDHD + jj])));
        }
        __syncthreads();
        if (threadIdx.x < 64) {
            int l = threadIdx.x;
            float s = 0.f;
#pragma unroll
            for (int x = 0; x < 32; ++x) {
                float kv = ks[l][x];
                s += kv * kv;
            }
            rn[l] = 1.f / fmaxf(sqrtf(s), 1e-12f);
        }
        __syncthreads();
        for (int lc = 0; lc < 64; ++lc) {
            float kj = ks[lc][j] * rn[lc];
            float ai = as_[lc][i], bi = bs[lc][i], vi = vs[lc][i], qj = qs[lc][j];
            S *= ai;
            float p = S * kj;
            p += __shfl_xor(p, 1);
            p += __shfl_xor(p, 2);
            p += __shfl_xor(p, 4);
            p += __shfl_xor(p, 8);
            p += __shfl_xor(p, 16);
            S += bi * (vi - p) * kj;
            float rd = S * qj;
            rd += __shfl_xor(rd, 1);
            rd += __shfl_xor(rd, 2);
            rd += __shfl_xor(rd, 4);
            rd += __shfl_xor(rd, 8);
            rd += __shfl_xor(rd, 16);
            if (j == 0) ctx[(size_t)(b * LSEQ + c0 + lc) * SDIMM + hh * SDHD + i] = rd;
        }
    }
    S_out[((size_t)(b * SHEAD + hh) * SDHD + i) * SDHD + j] = S;
}

// ------------- ctxbf = bf16(rmsnorm(ctx,nw)*silu(gate)), gate in P@1280 ----
__global__ void ctx_post(const float* __restrict__ ctx, const float* __restrict__ P,
                         const float* __restrict__ nw, bf16* __restrict__ out) {
    int row = blockIdx.x, t = threadIdx.x;  // 64 threads
    float4 x = ((const float4*)(ctx + (size_t)row * SDIMM))[t];
    float s = x.x * x.x + x.y * x.y + x.z * x.z + x.w * x.w;
    for (int m = 1; m < 64; m <<= 1) s += __shfl_xor(s, m);
    float r = rsqrtf(s * (1.f / 256.f) + 1e-6f);
    float4 n = ((const float4*)nw)[t];
    float4 g = ((const float4*)(P + (size_t)row * 1536 + 1280))[t];
    BF4 u;
    u.h[0] = (bf16)(x.x * r * n.x * (g.x / (1.f + __expf(-g.x))));
    u.h[1] = (bf16)(x.y * r * n.y * (g.y / (1.f + __expf(-g.y))));
    u.h[2] = (bf16)(x.z * r * n.z * (g.z / (1.f + __expf(-g.z))));
    u.h[3] = (bf16)(x.w * r * n.w * (g.w / (1.f + __expf(-g.w))));
    ((short4*)(out + (size_t)row * SDIMM))[t] = u.p;
}

// --------------- a1b = bf16(silu(gu[:, :1536]) * gu[:, 1536:]) -------------
__global__ void silu_mul_k(const bf16* __restrict__ gu, bf16* __restrict__ o, int total4) {
    int i = blockIdx.x * 256 + threadIdx.x;
    if (i >= total4) return;
    int tok = i / 384, c4 = i - tok * 384;
    BF4 gb, ub, ob;
    gb.p = ((const short4*)(gu + (size_t)tok * 3072))[c4];
    ub.p = ((const short4*)(gu + (size_t)tok * 3072 + 1536))[c4];
#pragma unroll
    for (int e = 0; e < 4; ++e) {
        float g = (float)gb.h[e], u = (float)ub.h[e];
        ob.h[e] = (bf16)(g / (1.f + __expf(-g)) * u);
    }
    ((short4*)o)[i] = ob.p;
}

// ---------------------------------------------------------------------------
extern "C" void kernel_launch(void* const* d_in, const int* in_sizes, int n_in,
                              void* d_out, int out_size, void* d_ws, size_t ws_size,
                              hipStream_t stream) {
    (void)in_sizes; (void)n_in; (void)out_size; (void)ws_size;
    const int* ids = (const int*)d_in[0];
    const float* state = (const float*)d_in[1];
    const float* embedw = (const float*)d_in[2];
    auto F = [&](int i) { return (const float*)d_in[i]; };

    char* wsb = (char*)d_ws;
    const size_t MB = 1048576;
    float* H    = (float*)(wsb);                 // 0-8 MB
    bf16*  XNbf = (bf16*)(wsb + 8 * MB);         // 8-12 (alias ctxf in delta)
    float* ctxf = (float*)(wsb + 8 * MB);
    bf16*  Hbf  = (bf16*)(wsb + 12 * MB);        // 12-16 (alias ctxb)
    bf16*  ctxb = (bf16*)(wsb + 12 * MB);
    float* P    = (float*)(wsb + 16 * MB);       // 16-40 (QKV f32 / delta f32 / GU bf16)
    bf16*  Pbf  = (bf16*)P;
    bf16*  Obf  = (bf16*)(wsb + 40 * MB);        // 40-44 attn out
    bf16*  Qbuf = (bf16*)(wsb + 44 * MB);        // 44-48
    bf16*  Kbuf = (bf16*)(wsb + 48 * MB);        // 48-52
    bf16*  Vtb  = (bf16*)(wsb + 52 * MB);        // 52-56
    bf16*  A1b  = (bf16*)(wsb + 44 * MB);        // alias Q/K/Vt (dead after attn)
    float* cosT = (float*)(wsb + 58 * MB);
    float* sinT = cosT + 32768;
    float* Sbuf = sinT + 32768;
    char*  wbase = wsb + 59 * MB;
    bf16* wqkv  = (bf16*)(wbase);                        // 6x1536x512
    bf16* wob   = (bf16*)(wbase + 9437184);              // 6x512x512
    bf16* wgu   = (bf16*)(wbase + 12582912);             // 6x3072x512
    bf16* wdnb  = (bf16*)(wbase + 31457280);             // 6x512x1536
    bf16* wdR   = (bf16*)(wbase + 40894464);             // 1536x512
    bf16* woutR = (bf16*)(wbase + 42467328);             // 512x256
    bf16* wdW   = (bf16*)(wbase + 42729472);             // 1536x512
    bf16* woutW = (bf16*)(wbase + 44302336);             // 512x256
    bf16* embp  = (bf16*)(wbase + 44564480);             // 128x512 padded

    float* out = (float*)d_out;
    float* logits = out;
    float* Sout = out + 4096 * VOCN;

    auto G = [&](int mode, const bf16* A, const bf16* B, float* C, bf16* Cb,
                 int M, int N, int K, int Nreal) {
        dim3 grid(N / 128, M / 128);
        if (mode == 0) gemm_bf16<0><<<grid, 256, 0, stream>>>(A, B, C, Cb, M, N, K, Nreal);
        else if (mode == 1) gemm_bf16<1><<<grid, 256, 0, stream>>>(A, B, C, Cb, M, N, K, Nreal);
        else gemm_bf16<3><<<grid, 256, 0, stream>>>(A, B, C, Cb, M, N, K, Nreal);
    };
    auto CP = [&](const float* s, bf16* d, int n4) {
        cast_plain<<<(n4 + 255) / 256, 256, 0, stream>>>(s, d, n4);
    };

    // ---- weight casts ----
    cast_fuse<<<1536, 256, 0, stream>>>(F(24), wqkv, 512, 128, 1536, 0, 393216);
    cast_fuse<<<1536, 256, 0, stream>>>(F(25), wqkv, 512, 128, 1536, 512, 393216);
    cast_fuse<<<1536, 256, 0, stream>>>(F(26), wqkv, 512, 128, 1536, 1024, 393216);
    CP(F(27), wob, 393216);
    cast_fuse<<<4608, 256, 0, stream>>>(F(29), wgu, 1536, 128, 3072, 0, 1179648);
    cast_fuse<<<4608, 256, 0, stream>>>(F(30), wgu, 1536, 128, 3072, 1536, 1179648);
    CP(F(31), wdnb, 1179648);
    cast6<<<768, 256, 0, stream>>>(F(3), F(4), F(5), F(6), F(8), F(12), wdR);
    CP(F(10), woutR, 32768);
    cast6<<<768, 256, 0, stream>>>(F(13), F(14), F(15), F(16), F(18), F(22), wdW);
    CP(F(20), woutW, 32768);
    cast_embed_pad<<<64, 256, 0, stream>>>(embedw, embp);

    rope_tables_k<<<128, 256, 0, stream>>>(cosT, sinT);
    embed_k<<<4096, 128, 0, stream>>>(ids, embedw, H);

    // ---- delta read ----
    CP(H, Hbf, 524288);
    G(0, Hbf, wdR, P, nullptr, 4096, 1536, 512, 1536);
    delta_scan<<<32, 1024, 0, stream>>>(P, state, F(7), F(9), Sbuf, ctxf);
    ctx_post<<<4096, 64, 0, stream>>>(ctxf, P, F(11), ctxb);
    G(1, ctxb, woutR, H, nullptr, 4096, 512, 256, 512);

    for (int i = 0; i < 6; ++i) {
        rmsnorm512<<<4096, 128, 0, stream>>>(H, F(23) + (size_t)i * 512, XNbf);
        G(0, XNbf, wqkv + (size_t)i * 1536 * 512, P, nullptr, 4096, 1536, 512, 1536);
        qkv_prep<<<4096, 256, 0, stream>>>(P, cosT, sinT, Qbuf, Kbuf, Vtb);
        attn_mfma<<<dim3(16, 8, 4), 256, 0, stream>>>(Qbuf, Kbuf, Vtb, Obf);
        G(1, Obf, wob + (size_t)i * 512 * 512, H, nullptr, 4096, 512, 512, 512);
        rmsnorm512<<<4096, 128, 0, stream>>>(H, F(28) + (size_t)i * 512, XNbf);
        G(3, XNbf, wgu + (size_t)i * 3072 * 512, nullptr, Pbf, 4096, 3072, 512, 3072);
        silu_mul_k<<<6144, 256, 0, stream>>>(Pbf, A1b, 1572864);
        G(1, A1b, wdnb + (size_t)i * 512 * 1536, H, nullptr, 4096, 512, 1536, 512);
    }

    // ---- delta write ----
    CP(H, Hbf, 524288);
    G(0, Hbf, wdW, P, nullptr, 4096, 1536, 512, 1536);
    delta_scan<<<32, 1024, 0, stream>>>(P, Sbuf, F(17), F(19), Sout, ctxf);
    ctx_post<<<4096, 64, 0, stream>>>(ctxf, P, F(21), ctxb);
    G(1, ctxb, woutW, H, nullptr, 4096, 512, 256, 512);

    rmsnorm512<<<4096, 128, 0, stream>>>(H, F(32), XNbf);
    G(0, XNbf, embp, logits, nullptr, 4096, 128, 512, VOCN);
}

// Round 4
// 2247.378 us; speedup vs baseline: 5.6494x; 1.1131x over previous
//
#include <hip/hip_runtime.h>
#include <hip/hip_bf16.h>
#include <math.h>

// ---------------------------------------------------------------------------
// BashTransformer forward on MI355X. Round 4: register-resident delta scan
// (1 wave per (b,h), S in VGPRs, single-shfl reductions), MFMA flash attn,
// bf16 MFMA GEMMs (m97 structure), fused projections.
// ---------------------------------------------------------------------------

#define LSEQ 1024
#define BATCH 4
#define HIDDEN 512
#define NHEAD 8
#define HDIM 64
#define SHEAD 8
#define SDHD 32
#define SDIMM 256
#define FFND 1536
#define VOCN 63
#define ATTS 72   // attn LDS row stride (elems): 144B = 16B-aligned, 2-way banks

typedef __bf16 bf16;
typedef __attribute__((ext_vector_type(8))) __bf16 bf16x8;
typedef __attribute__((ext_vector_type(4))) float floatx4;

union BF4 { bf16 h[4]; short4 p; };

__device__ __forceinline__ void gload16(const void* g, const void* l) {
    __builtin_amdgcn_global_load_lds(
        (__attribute__((address_space(1))) unsigned int*)(uintptr_t)g,
        (__attribute__((address_space(3))) unsigned int*)(unsigned int)(uintptr_t)l,
        16, 0, 0);
}

// ------------------------------- rope tables -------------------------------
__global__ void rope_tables_k(float* __restrict__ cosT, float* __restrict__ sinT) {
    int idx = blockIdx.x * 256 + threadIdx.x;   // 32768 = 1024*32
    int l = idx >> 5, d = idx & 31;
    double ang = (double)l * pow(500000.0, -(double)(2 * d) / 64.0);
    cosT[idx] = (float)cos(ang);
    sinT[idx] = (float)sin(ang);
}

// ------------------------------- embedding ---------------------------------
__global__ void embed_k(const int* __restrict__ ids, const float* __restrict__ emb,
                        float* __restrict__ h) {
    int tok = blockIdx.x;
    int id = ids[tok];
    ((float4*)(h + (size_t)tok * HIDDEN))[threadIdx.x] =
        ((const float4*)(emb + (size_t)id * HIDDEN))[threadIdx.x];
}

// ------------------------------- casts -------------------------------------
__global__ void cast_plain(const float* __restrict__ s, bf16* __restrict__ d, int n4) {
    int i = blockIdx.x * 256 + threadIdx.x;
    if (i >= n4) return;
    float4 v = ((const float4*)s)[i];
    BF4 u;
    u.h[0] = (bf16)v.x; u.h[1] = (bf16)v.y; u.h[2] = (bf16)v.z; u.h[3] = (bf16)v.w;
    ((short4*)d)[i] = u.p;
}

// six 256x512 f32 matrices -> one fused 1536x512 bf16 (order s0..s5)
__global__ void cast6(const float* s0, const float* s1, const float* s2,
                      const float* s3, const float* s4, const float* s5,
                      bf16* __restrict__ d) {
    int i = blockIdx.x * 256 + threadIdx.x;      // 196608 short4s
    if (i >= 196608) return;
    int which = i >> 15, loc = i & 32767;
    const float* s = which == 0 ? s0 : which == 1 ? s1 : which == 2 ? s2
                    : which == 3 ? s3 : which == 4 ? s4 : s5;
    float4 v = ((const float4*)s)[loc];
    BF4 u;
    u.h[0] = (bf16)v.x; u.h[1] = (bf16)v.y; u.h[2] = (bf16)v.z; u.h[3] = (bf16)v.w;
    ((short4*)d)[i] = u.p;
}

// gather (layers,R,K) f32 -> fused bf16 rows [i*dstStride + dstOff + r]
__global__ void cast_fuse(const float* __restrict__ s, bf16* __restrict__ d,
                          int R, int K4, int dstStride, int dstOff, int total4) {
    int idx = blockIdx.x * 256 + threadIdx.x;
    if (idx >= total4) return;
    int perLayer = R * K4;
    int i = idx / perLayer;
    int rem = idx - i * perLayer;
    int r = rem / K4, c4 = rem - r * K4;
    float4 v = ((const float4*)s)[idx];
    BF4 u;
    u.h[0] = (bf16)v.x; u.h[1] = (bf16)v.y; u.h[2] = (bf16)v.z; u.h[3] = (bf16)v.w;
    ((short4*)d)[((size_t)i * dstStride + dstOff + r) * K4 + c4] = u.p;
}

__global__ void cast_embed_pad(const float* __restrict__ s, bf16* __restrict__ d) {
    int i = blockIdx.x * 256 + threadIdx.x;   // 128*128 = 16384 short4s
    int row = i >> 7, c4 = i & 127;
    BF4 u;
    if (row < VOCN) {
        float4 v = ((const float4*)s)[row * 128 + c4];
        u.h[0] = (bf16)v.x; u.h[1] = (bf16)v.y; u.h[2] = (bf16)v.z; u.h[3] = (bf16)v.w;
    } else {
        u.h[0] = (bf16)0.f; u.h[1] = (bf16)0.f; u.h[2] = (bf16)0.f; u.h[3] = (bf16)0.f;
    }
    ((short4*)d)[i] = u.p;
}

// ------------------------------- rmsnorm -> bf16 ---------------------------
__global__ void rmsnorm512(const float* __restrict__ in, const float* __restrict__ w,
                           bf16* __restrict__ out) {
    int row = blockIdx.x, t = threadIdx.x;     // 128 threads
    float4 x = ((const float4*)(in + (size_t)row * 512))[t];
    float s = x.x * x.x + x.y * x.y + x.z * x.z + x.w * x.w;
    for (int m = 1; m < 64; m <<= 1) s += __shfl_xor(s, m);
    __shared__ float red[2];
    if ((t & 63) == 0) red[t >> 6] = s;
    __syncthreads();
    float tot = red[0] + red[1];
    float r = rsqrtf(tot * (1.f / 512.f) + 1e-6f);
    float4 wv = ((const float4*)w)[t];
    BF4 u;
    u.h[0] = (bf16)(x.x * r * wv.x); u.h[1] = (bf16)(x.y * r * wv.y);
    u.h[2] = (bf16)(x.z * r * wv.z); u.h[3] = (bf16)(x.w * r * wv.w);
    ((short4*)(out + (size_t)row * 512))[t] = u.p;
}

// ------------------------------- bf16 MFMA GEMM ----------------------------
// C = A(bf16, MxK rm) @ B(bf16, NxK rm)^T. 128x128 tile, Kstep 32, 4 waves.
// MODE 0: C(f32)=v  MODE 1: C(f32)+=v  MODE 3: Cb(bf16)=v
template <int MODE>
__global__ __launch_bounds__(256) void gemm_bf16(const bf16* __restrict__ A,
                                                 const bf16* __restrict__ B,
                                                 float* __restrict__ C,
                                                 bf16* __restrict__ Cb,
                                                 int M, int N, int K, int Nreal) {
    __shared__ bf16 As[128 * 32];
    __shared__ bf16 Bs[128 * 32];
    const int tid = threadIdx.x;
    const int wave = tid >> 6, lane = tid & 63;
    const int row0 = blockIdx.y * 128, col0 = blockIdx.x * 128;
    floatx4 acc[4][4];
#pragma unroll
    for (int i = 0; i < 4; ++i)
#pragma unroll
        for (int j = 0; j < 4; ++j) acc[i][j] = (floatx4){0.f, 0.f, 0.f, 0.f};
    const int m0 = (wave & 1) * 64, n0 = (wave >> 1) * 64;
    const int sr = tid >> 2;
    const int ske = (tid & 3) * 8;
    const size_t arow1 = (size_t)(row0 + sr) * K + ske;
    const size_t arow2 = (size_t)(row0 + 64 + sr) * K + ske;
    const size_t brow1 = (size_t)(col0 + sr) * K + ske;
    const size_t brow2 = (size_t)(col0 + 64 + sr) * K + ske;
    char* AsB = (char*)As;
    char* BsB = (char*)Bs;
    const int lds0 = wave * 1024, lds1 = 4096 + wave * 1024;

    for (int k0 = 0; k0 < K; k0 += 32) {
        gload16(A + arow1 + k0, AsB + lds0);
        gload16(A + arow2 + k0, AsB + lds1);
        gload16(B + brow1 + k0, BsB + lds0);
        gload16(B + brow2 + k0, BsB + lds1);
        __syncthreads();
        bf16x8 af[4], bfr[4];
#pragma unroll
        for (int mi = 0; mi < 4; ++mi)
            af[mi] = *(const bf16x8*)(AsB + ((m0 + mi * 16 + (lane & 15)) * 32 + (lane >> 4) * 8) * 2);
#pragma unroll
        for (int ni = 0; ni < 4; ++ni)
            bfr[ni] = *(const bf16x8*)(BsB + ((n0 + ni * 16 + (lane & 15)) * 32 + (lane >> 4) * 8) * 2);
#pragma unroll
        for (int mi = 0; mi < 4; ++mi)
#pragma unroll
            for (int ni = 0; ni < 4; ++ni)
                acc[mi][ni] = __builtin_amdgcn_mfma_f32_16x16x32_bf16(af[mi], bfr[ni], acc[mi][ni], 0, 0, 0);
        __syncthreads();
    }
    const int cr = (lane >> 4) * 4;
    const int cc = lane & 15;
#pragma unroll
    for (int mi = 0; mi < 4; ++mi) {
#pragma unroll
        for (int ni = 0; ni < 4; ++ni) {
#pragma unroll
            for (int r = 0; r < 4; ++r) {
                int row = row0 + m0 + mi * 16 + cr + r;
                int col = col0 + n0 + ni * 16 + cc;
                if (col < Nreal) {
                    size_t o = (size_t)row * Nreal + col;
                    float v = acc[mi][ni][r];
                    if (MODE == 0) C[o] = v;
                    else if (MODE == 1) C[o] += v;
                    else if (MODE == 3) Cb[o] = (bf16)v;
                }
            }
        }
    }
}

// ----------------- QKV prep: RoPE + bf16 cast + V transpose ----------------
__global__ void qkv_prep(const float* __restrict__ P, const float* __restrict__ cosT,
                         const float* __restrict__ sinT, bf16* __restrict__ Qb,
                         bf16* __restrict__ Kb, bf16* __restrict__ Vtb) {
    int tok = blockIdx.x;                       // 4096
    int b = tok >> 10, l = tok & 1023;
    int hh = threadIdx.x >> 5, d = threadIdx.x & 31;
    const float* q = P + (size_t)tok * 1536 + hh * 64;
    const float* k = q + 512;
    const float* v = q + 1024;
    float c = cosT[l * 32 + d], s = sinT[l * 32 + d];
    size_t base = ((size_t)(b * 8 + hh) * 1024 + l) * 64;
    float q1 = q[d], q2 = q[d + 32];
    Qb[base + d] = (bf16)(q1 * c - q2 * s);
    Qb[base + d + 32] = (bf16)(q2 * c + q1 * s);
    float k1 = k[d], k2 = k[d + 32];
    Kb[base + d] = (bf16)(k1 * c - k2 * s);
    Kb[base + d + 32] = (bf16)(k2 * c + k1 * s);
    size_t vb = (size_t)(b * 8 + hh) * 64 * 1024 + l;
    Vtb[vb + (size_t)d * 1024] = (bf16)v[d];
    Vtb[vb + (size_t)(d + 32) * 1024] = (bf16)v[d + 32];
}

// ------------------------- MFMA flash attention ----------------------------
__global__ __launch_bounds__(256) void attn_mfma(const bf16* __restrict__ Qb,
                                                 const bf16* __restrict__ Kb,
                                                 const bf16* __restrict__ Vtb,
                                                 bf16* __restrict__ O) {
    int qt = blockIdx.x, hh = blockIdx.y, b = blockIdx.z;
    int bh = b * 8 + hh;
    int q0 = qt * 64;
    const bf16* Qg = Qb + ((size_t)bh * 1024 + q0) * 64;
    const bf16* Kg = Kb + (size_t)bh * 1024 * 64;
    const bf16* Vg = Vtb + (size_t)bh * 64 * 1024;   // [64 d][1024 l]
    __shared__ bf16 Qs[64 * ATTS];
    __shared__ bf16 Ks[64 * ATTS];
    __shared__ bf16 Vs[64 * ATTS];
    __shared__ bf16 Ps[64 * ATTS];
    int tid = threadIdx.x, wave = tid >> 6, lane = tid & 63;
    int lr = lane & 15, quad = lane >> 4;

#pragma unroll
    for (int it = 0; it < 2; ++it) {
        int cidx = tid + it * 256;
        int row = cidx >> 3, ch = cidx & 7;
        *(bf16x8*)(Qs + row * ATTS + ch * 8) = *(const bf16x8*)(Qg + row * 64 + ch * 8);
    }
    float mrow[4], lrow[4];
    floatx4 Oacc[4];
#pragma unroll
    for (int r = 0; r < 4; ++r) { mrow[r] = -1e30f; lrow[r] = 0.f; }
#pragma unroll
    for (int d0 = 0; d0 < 4; ++d0) Oacc[d0] = (floatx4){0.f, 0.f, 0.f, 0.f};

    int ntiles = qt + 1;
    for (int t = 0; t < ntiles; ++t) {
        int kv0 = t * 64;
        __syncthreads();
#pragma unroll
        for (int it = 0; it < 2; ++it) {
            int cidx = tid + it * 256;
            int row = cidx >> 3, ch = cidx & 7;
            *(bf16x8*)(Ks + row * ATTS + ch * 8) =
                *(const bf16x8*)(Kg + (size_t)(kv0 + row) * 64 + ch * 8);
            *(bf16x8*)(Vs + row * ATTS + ch * 8) =
                *(const bf16x8*)(Vg + (size_t)row * 1024 + kv0 + ch * 8);
        }
        __syncthreads();
        bf16x8 aq[2];
#pragma unroll
        for (int kc = 0; kc < 2; ++kc)
            aq[kc] = *(const bf16x8*)(Qs + (wave * 16 + lr) * ATTS + kc * 32 + quad * 8);
        floatx4 sacc[4];
#pragma unroll
        for (int n0 = 0; n0 < 4; ++n0) {
            bf16x8 bk0 = *(const bf16x8*)(Ks + (n0 * 16 + lr) * ATTS + quad * 8);
            bf16x8 bk1 = *(const bf16x8*)(Ks + (n0 * 16 + lr) * ATTS + 32 + quad * 8);
            floatx4 z = (floatx4){0.f, 0.f, 0.f, 0.f};
            z = __builtin_amdgcn_mfma_f32_16x16x32_bf16(aq[0], bk0, z, 0, 0, 0);
            sacc[n0] = __builtin_amdgcn_mfma_f32_16x16x32_bf16(aq[1], bk1, z, 0, 0, 0);
        }
        float sv[4][4];
#pragma unroll
        for (int n0 = 0; n0 < 4; ++n0)
#pragma unroll
            for (int r = 0; r < 4; ++r) sv[n0][r] = sacc[n0][r] * 0.125f;
        if (t == ntiles - 1) {
#pragma unroll
            for (int n0 = 0; n0 < 4; ++n0)
#pragma unroll
                for (int r = 0; r < 4; ++r)
                    if (n0 * 16 + lr > wave * 16 + quad * 4 + r) sv[n0][r] = -1e30f;
        }
        float al[4];
#pragma unroll
        for (int r = 0; r < 4; ++r) {
            float tm = fmaxf(fmaxf(sv[0][r], sv[1][r]), fmaxf(sv[2][r], sv[3][r]));
            tm = fmaxf(tm, __shfl_xor(tm, 1));
            tm = fmaxf(tm, __shfl_xor(tm, 2));
            tm = fmaxf(tm, __shfl_xor(tm, 4));
            tm = fmaxf(tm, __shfl_xor(tm, 8));
            float mn = fmaxf(mrow[r], tm);
            al[r] = __expf(mrow[r] - mn);
            mrow[r] = mn;
        }
        float rs[4];
#pragma unroll
        for (int r = 0; r < 4; ++r) rs[r] = 0.f;
#pragma unroll
        for (int n0 = 0; n0 < 4; ++n0)
#pragma unroll
            for (int r = 0; r < 4; ++r) {
                float p = __expf(sv[n0][r] - mrow[r]);
                sv[n0][r] = p;
                rs[r] += p;
            }
#pragma unroll
        for (int r = 0; r < 4; ++r) {
            float t2 = rs[r];
            t2 += __shfl_xor(t2, 1);
            t2 += __shfl_xor(t2, 2);
            t2 += __shfl_xor(t2, 4);
            t2 += __shfl_xor(t2, 8);
            lrow[r] = lrow[r] * al[r] + t2;
        }
#pragma unroll
        for (int d0 = 0; d0 < 4; ++d0)
#pragma unroll
            for (int r = 0; r < 4; ++r) Oacc[d0][r] *= al[r];
#pragma unroll
        for (int n0 = 0; n0 < 4; ++n0)
#pragma unroll
            for (int r = 0; r < 4; ++r)
                Ps[(wave * 16 + quad * 4 + r) * ATTS + n0 * 16 + lr] = (bf16)sv[n0][r];
        bf16x8 ap[2];
#pragma unroll
        for (int kc = 0; kc < 2; ++kc)
            ap[kc] = *(const bf16x8*)(Ps + (wave * 16 + lr) * ATTS + kc * 32 + quad * 8);
#pragma unroll
        for (int d0 = 0; d0 < 4; ++d0) {
            bf16x8 bv0 = *(const bf16x8*)(Vs + (d0 * 16 + lr) * ATTS + quad * 8);
            bf16x8 bv1 = *(const bf16x8*)(Vs + (d0 * 16 + lr) * ATTS + 32 + quad * 8);
            Oacc[d0] = __builtin_amdgcn_mfma_f32_16x16x32_bf16(ap[0], bv0, Oacc[d0], 0, 0, 0);
            Oacc[d0] = __builtin_amdgcn_mfma_f32_16x16x32_bf16(ap[1], bv1, Oacc[d0], 0, 0, 0);
        }
    }
    float inv[4];
#pragma unroll
    for (int r = 0; r < 4; ++r) inv[r] = 1.f / lrow[r];
#pragma unroll
    for (int d0 = 0; d0 < 4; ++d0)
#pragma unroll
        for (int r = 0; r < 4; ++r) {
            int row = b * 1024 + q0 + wave * 16 + quad * 4 + r;
            int col = hh * 64 + d0 * 16 + lr;
            O[(size_t)row * 512 + col] = (bf16)(Oacc[d0][r] * inv[r]);
        }
}

// ------------------------------- delta scan --------------------------------
// One wave per (b,h). Lane = (half = l>>5, i = l&31) owns S[i][half*16..+16)
// in 16 VGPRs. pred = a_i*(S_old.k); S_new = a_i*S_old + u k^T (decay folded).
// k pre-normalized in LDS per chunk; sigmoid+bias applied at staging.
__global__ __launch_bounds__(64) void delta_scan(
    const float* __restrict__ P, const float* __restrict__ S_in,
    const float* __restrict__ bbias, const float* __restrict__ abias,
    float* __restrict__ S_out, float* __restrict__ ctx) {
    int b = blockIdx.x >> 3, hh = blockIdx.x & 7;
    int lane = threadIdx.x;
    int i = lane & 31, half = lane >> 5;
    __shared__ float ks[64][36], vs[64][36], qs[64][36], bs[64][36], as_[64][36];

    const float* Sp = S_in + (((size_t)(b * SHEAD + hh) * SDHD + i) * SDHD) + half * 16;
    float4 S0 = *(const float4*)(Sp);
    float4 S1 = *(const float4*)(Sp + 4);
    float4 S2 = *(const float4*)(Sp + 8);
    float4 S3 = *(const float4*)(Sp + 12);

    int c4 = lane & 7, r0 = lane >> 3;
    float4 biasB = *(const float4*)(bbias + hh * SDHD + c4 * 4);
    float4 biasA = *(const float4*)(abias + hh * SDHD + c4 * 4);

    for (int c0 = 0; c0 < LSEQ; c0 += 64) {
        __syncthreads();
        const float* Pb = P + ((size_t)(b * LSEQ + c0) * 1536) + hh * SDHD + c4 * 4;
#pragma unroll
        for (int it = 0; it < 8; ++it) {
            int row = r0 + it * 8;
            const float* pg = Pb + (size_t)row * 1536;
            float4 kv = *(const float4*)(pg);
            float4 vv = *(const float4*)(pg + 256);
            float4 qv = *(const float4*)(pg + 512);
            float4 bv = *(const float4*)(pg + 768);
            float4 av = *(const float4*)(pg + 1024);
            *(float4*)&ks[row][c4 * 4] = kv;
            *(float4*)&vs[row][c4 * 4] = vv;
            *(float4*)&qs[row][c4 * 4] = qv;
            float4 bo, ao;
            bo.x = 1.f / (1.f + __expf(-(bv.x + biasB.x)));
            bo.y = 1.f / (1.f + __expf(-(bv.y + biasB.y)));
            bo.z = 1.f / (1.f + __expf(-(bv.z + biasB.z)));
            bo.w = 1.f / (1.f + __expf(-(bv.w + biasB.w)));
            ao.x = 1.f / (1.f + __expf(-(av.x + biasA.x)));
            ao.y = 1.f / (1.f + __expf(-(av.y + biasA.y)));
            ao.z = 1.f / (1.f + __expf(-(av.z + biasA.z)));
            ao.w = 1.f / (1.f + __expf(-(av.w + biasA.w)));
            *(float4*)&bs[row][c4 * 4] = bo;
            *(float4*)&as_[row][c4 * 4] = ao;
        }
        __syncthreads();
        // normalize k row `lane` in place (rotated index -> conflict-free)
        {
            float s = 0.f;
#pragma unroll
            for (int x = 0; x < 32; ++x) {
                float kv = ks[lane][(x + lane) & 31];
                s += kv * kv;
            }
            float r = 1.f / fmaxf(sqrtf(s), 1e-12f);
#pragma unroll
            for (int x = 0; x < 32; ++x) ks[lane][(x + lane) & 31] *= r;
        }
        __syncthreads();
        for (int t = 0; t < 64; ++t) {
            const float* kr = &ks[t][half * 16];
            float4 k0 = *(const float4*)(kr);
            float4 k1 = *(const float4*)(kr + 4);
            float4 k2 = *(const float4*)(kr + 8);
            float4 k3 = *(const float4*)(kr + 12);
            float a = as_[t][i], bb = bs[t][i], vv = vs[t][i];
            float dx = S0.x * k0.x + S0.y * k0.y + S0.z * k0.z + S0.w * k0.w;
            float dy = S1.x * k1.x + S1.y * k1.y + S1.z * k1.z + S1.w * k1.w;
            float dz = S2.x * k2.x + S2.y * k2.y + S2.z * k2.z + S2.w * k2.w;
            float dw = S3.x * k3.x + S3.y * k3.y + S3.z * k3.z + S3.w * k3.w;
            float dot = (dx + dy) + (dz + dw);
            dot += __shfl_xor(dot, 32);
            float u = bb * (vv - a * dot);
            S0.x = a * S0.x + u * k0.x; S0.y = a * S0.y + u * k0.y;
            S0.z = a * S0.z + u * k0.z; S0.w = a * S0.w + u * k0.w;
            S1.x = a * S1.x + u * k1.x; S1.y = a * S1.y + u * k1.y;
            S1.z = a * S1.z + u * k1.z; S1.w = a * S1.w + u * k1.w;
            S2.x = a * S2.x + u * k2.x; S2.y = a * S2.y + u * k2.y;
            S2.z = a * S2.z + u * k2.z; S2.w = a * S2.w + u * k2.w;
            S3.x = a * S3.x + u * k3.x; S3.y = a * S3.y + u * k3.y;
            S3.z = a * S3.z + u * k3.z; S3.w = a * S3.w + u * k3.w;
            const float* qr = &qs[t][half * 16];
            float4 q0 = *(const float4*)(qr);
            float4 q1 = *(const float4*)(qr + 4);
            float4 q2 = *(const float4*)(qr + 8);
            float4 q3 = *(const float4*)(qr + 12);
            float rx = S0.x * q0.x + S0.y * q0.y + S0.z * q0.z + S0.w * q0.w;
            float ry = S1.x * q1.x + S1.y * q1.y + S1.z * q1.z + S1.w * q1.w;
            float rz = S2.x * q2.x + S2.y * q2.y + S2.z * q2.z + S2.w * q2.w;
            float rw = S3.x * q3.x + S3.y * q3.y + S3.z * q3.z + S3.w * q3.w;
            float rd = (rx + ry) + (rz + rw);
            rd += __shfl_xor(rd, 32);
            if (half == 0)
                ctx[(size_t)(b * LSEQ + c0 + t) * SDIMM + hh * SDHD + i] = rd;
        }
    }
    float* So = S_out + (((size_t)(b * SHEAD + hh) * SDHD + i) * SDHD) + half * 16;
    *(float4*)(So) = S0;
    *(float4*)(So + 4) = S1;
    *(float4*)(So + 8) = S2;
    *(float4*)(So + 12) = S3;
}

// ------------- ctxbf = bf16(rmsnorm(ctx,nw)*silu(gate)), gate in P@1280 ----
__global__ void ctx_post(const float* __restrict__ ctx, const float* __restrict__ P,
                         const float* __restrict__ nw, bf16* __restrict__ out) {
    int row = blockIdx.x, t = threadIdx.x;  // 64 threads
    float4 x = ((const float4*)(ctx + (size_t)row * SDIMM))[t];
    float s = x.x * x.x + x.y * x.y + x.z * x.z + x.w * x.w;
    for (int m = 1; m < 64; m <<= 1) s += __shfl_xor(s, m);
    float r = rsqrtf(s * (1.f / 256.f) + 1e-6f);
    float4 n = ((const float4*)nw)[t];
    float4 g = ((const float4*)(P + (size_t)row * 1536 + 1280))[t];
    BF4 u;
    u.h[0] = (bf16)(x.x * r * n.x * (g.x / (1.f + __expf(-g.x))));
    u.h[1] = (bf16)(x.y * r * n.y * (g.y / (1.f + __expf(-g.y))));
    u.h[2] = (bf16)(x.z * r * n.z * (g.z / (1.f + __expf(-g.z))));
    u.h[3] = (bf16)(x.w * r * n.w * (g.w / (1.f + __expf(-g.w))));
    ((short4*)(out + (size_t)row * SDIMM))[t] = u.p;
}

// --------------- a1b = bf16(silu(gu[:, :1536]) * gu[:, 1536:]) -------------
__global__ void silu_mul_k(const bf16* __restrict__ gu, bf16* __restrict__ o, int total4) {
    int i = blockIdx.x * 256 + threadIdx.x;
    if (i >= total4) return;
    int tok = i / 384, c4 = i - tok * 384;
    BF4 gb, ub, ob;
    gb.p = ((const short4*)(gu + (size_t)tok * 3072))[c4];
    ub.p = ((const short4*)(gu + (size_t)tok * 3072 + 1536))[c4];
#pragma unroll
    for (int e = 0; e < 4; ++e) {
        float g = (float)gb.h[e], u = (float)ub.h[e];
        ob.h[e] = (bf16)(g / (1.f + __expf(-g)) * u);
    }
    ((short4*)o)[i] = ob.p;
}

// ---------------------------------------------------------------------------
extern "C" void kernel_launch(void* const* d_in, const int* in_sizes, int n_in,
                              void* d_out, int out_size, void* d_ws, size_t ws_size,
                              hipStream_t stream) {
    (void)in_sizes; (void)n_in; (void)out_size; (void)ws_size;
    const int* ids = (const int*)d_in[0];
    const float* state = (const float*)d_in[1];
    const float* embedw = (const float*)d_in[2];
    auto F = [&](int i) { return (const float*)d_in[i]; };

    char* wsb = (char*)d_ws;
    const size_t MB = 1048576;
    float* H    = (float*)(wsb);                 // 0-8 MB
    bf16*  XNbf = (bf16*)(wsb + 8 * MB);         // 8-12 (alias ctxf in delta)
    float* ctxf = (float*)(wsb + 8 * MB);
    bf16*  Hbf  = (bf16*)(wsb + 12 * MB);        // 12-16 (alias ctxb)
    bf16*  ctxb = (bf16*)(wsb + 12 * MB);
    float* P    = (float*)(wsb + 16 * MB);       // 16-40 (QKV f32 / delta f32 / GU bf16)
    bf16*  Pbf  = (bf16*)P;
    bf16*  Obf  = (bf16*)(wsb + 40 * MB);        // 40-44 attn out
    bf16*  Qbuf = (bf16*)(wsb + 44 * MB);        // 44-48
    bf16*  Kbuf = (bf16*)(wsb + 48 * MB);        // 48-52
    bf16*  Vtb  = (bf16*)(wsb + 52 * MB);        // 52-56
    bf16*  A1b  = (bf16*)(wsb + 44 * MB);        // alias Q/K/Vt (dead after attn)
    float* cosT = (float*)(wsb + 58 * MB);
    float* sinT = cosT + 32768;
    float* Sbuf = sinT + 32768;
    char*  wbase = wsb + 59 * MB;
    bf16* wqkv  = (bf16*)(wbase);                        // 6x1536x512
    bf16* wob   = (bf16*)(wbase + 9437184);              // 6x512x512
    bf16* wgu   = (bf16*)(wbase + 12582912);             // 6x3072x512
    bf16* wdnb  = (bf16*)(wbase + 31457280);             // 6x512x1536
    bf16* wdR   = (bf16*)(wbase + 40894464);             // 1536x512
    bf16* woutR = (bf16*)(wbase + 42467328);             // 512x256
    bf16* wdW   = (bf16*)(wbase + 42729472);             // 1536x512
    bf16* woutW = (bf16*)(wbase + 44302336);             // 512x256
    bf16* embp  = (bf16*)(wbase + 44564480);             // 128x512 padded

    float* out = (float*)d_out;
    float* logits = out;
    float* Sout = out + 4096 * VOCN;

    auto G = [&](int mode, const bf16* A, const bf16* B, float* C, bf16* Cb,
                 int M, int N, int K, int Nreal) {
        dim3 grid(N / 128, M / 128);
        if (mode == 0) gemm_bf16<0><<<grid, 256, 0, stream>>>(A, B, C, Cb, M, N, K, Nreal);
        else if (mode == 1) gemm_bf16<1><<<grid, 256, 0, stream>>>(A, B, C, Cb, M, N, K, Nreal);
        else gemm_bf16<3><<<grid, 256, 0, stream>>>(A, B, C, Cb, M, N, K, Nreal);
    };
    auto CP = [&](const float* s, bf16* d, int n4) {
        cast_plain<<<(n4 + 255) / 256, 256, 0, stream>>>(s, d, n4);
    };

    // ---- weight casts ----
    cast_fuse<<<1536, 256, 0, stream>>>(F(24), wqkv, 512, 128, 1536, 0, 393216);
    cast_fuse<<<1536, 256, 0, stream>>>(F(25), wqkv, 512, 128, 1536, 512, 393216);
    cast_fuse<<<1536, 256, 0, stream>>>(F(26), wqkv, 512, 128, 1536, 1024, 393216);
    CP(F(27), wob, 393216);
    cast_fuse<<<4608, 256, 0, stream>>>(F(29), wgu, 1536, 128, 3072, 0, 1179648);
    cast_fuse<<<4608, 256, 0, stream>>>(F(30), wgu, 1536, 128, 3072, 1536, 1179648);
    CP(F(31), wdnb, 1179648);
    cast6<<<768, 256, 0, stream>>>(F(3), F(4), F(5), F(6), F(8), F(12), wdR);
    CP(F(10), woutR, 32768);
    cast6<<<768, 256, 0, stream>>>(F(13), F(14), F(15), F(16), F(18), F(22), wdW);
    CP(F(20), woutW, 32768);
    cast_embed_pad<<<64, 256, 0, stream>>>(embedw, embp);

    rope_tables_k<<<128, 256, 0, stream>>>(cosT, sinT);
    embed_k<<<4096, 128, 0, stream>>>(ids, embedw, H);

    // ---- delta read ----
    CP(H, Hbf, 524288);
    G(0, Hbf, wdR, P, nullptr, 4096, 1536, 512, 1536);
    delta_scan<<<32, 64, 0, stream>>>(P, state, F(7), F(9), Sbuf, ctxf);
    ctx_post<<<4096, 64, 0, stream>>>(ctxf, P, F(11), ctxb);
    G(1, ctxb, woutR, H, nullptr, 4096, 512, 256, 512);

    for (int i = 0; i < 6; ++i) {
        rmsnorm512<<<4096, 128, 0, stream>>>(H, F(23) + (size_t)i * 512, XNbf);
        G(0, XNbf, wqkv + (size_t)i * 1536 * 512, P, nullptr, 4096, 1536, 512, 1536);
        qkv_prep<<<4096, 256, 0, stream>>>(P, cosT, sinT, Qbuf, Kbuf, Vtb);
        attn_mfma<<<dim3(16, 8, 4), 256, 0, stream>>>(Qbuf, Kbuf, Vtb, Obf);
        G(1, Obf, wob + (size_t)i * 512 * 512, H, nullptr, 4096, 512, 512, 512);
        rmsnorm512<<<4096, 128, 0, stream>>>(H, F(28) + (size_t)i * 512, XNbf);
        G(3, XNbf, wgu + (size_t)i * 3072 * 512, nullptr, Pbf, 4096, 3072, 512, 3072);
        silu_mul_k<<<6144, 256, 0, stream>>>(Pbf, A1b, 1572864);
        G(1, A1b, wdnb + (size_t)i * 512 * 1536, H, nullptr, 4096, 512, 1536, 512);
    }

    // ---- delta write ----
    CP(H, Hbf, 524288);
    G(0, Hbf, wdW, P, nullptr, 4096, 1536, 512, 1536);
    delta_scan<<<32, 64, 0, stream>>>(P, Sbuf, F(17), F(19), Sout, ctxf);
    ctx_post<<<4096, 64, 0, stream>>>(ctxf, P, F(21), ctxb);
    G(1, ctxb, woutW, H, nullptr, 4096, 512, 256, 512);

    rmsnorm512<<<4096, 128, 0, stream>>>(H, F(32), XNbf);
    G(0, XNbf, embp, logits, nullptr, 4096, 128, 512, VOCN);
}